// Round 8
// baseline (420.432 us; speedup 1.0000x reference)
//
#include <hip/hip_runtime.h>
#include <math.h>

#define DIM 64
#define NBLK 512         // blocks in count/place passes; 2 blocks/CU
#define NTHR 1024
#define KMAX 4096        // max buckets; K = ceil((2U+I)/64) = 3907
#define NSEG 8           // base-pass segments (NBLK/NSEG = 64 blocks per segment)
#define SEGW (NBLK / NSEG)
#define SCH  4096        // scan chunk = NTHR*4; supports R <= 64*4096 = 262144 (R = 250001)

typedef unsigned short ushort_t;
typedef unsigned int uint_t;
typedef unsigned char uchar_t;
typedef float v2f __attribute__((ext_vector_type(2)));

__device__ __forceinline__ ushort_t f2bf(float f) {
    uint_t u = __float_as_uint(f);
    return (ushort_t)((u + 0x7fffu + ((u >> 16) & 1u)) >> 16);
}

// ---------------- pass 1: fp8 tables + bucket histogram (LDS) + row degrees (global) ---------
// fp8: emb ~N(0,0.01^2) x256 in e4m3 normal range (verified absmax 0.0 since R6).
// R5 lesson: two-level (block x bucket) scheme is load-bearing for place's write locality.
// R19: edge reads vectorized x4 (int4); deg[r] atomics added -> ptr computed by scan,
// deleting finalize's histogram pass and the single-block bucketPtr scan.

__device__ __forceinline__ void count_list(const int* __restrict__ rows, int EL, int base,
                                           int* h, int* __restrict__ deg,
                                           size_t gtid, size_t GT) {
    size_t nq = ((size_t)EL + 3) >> 2;
    for (size_t q = gtid; q < nq; q += GT) {
        int e = (int)(q << 2);
        if (e + 4 <= EL) {
            int4 r4 = *(const int4*)(rows + e);
            int v0 = base + r4.x, v1 = base + r4.y, v2 = base + r4.z, v3 = base + r4.w;
            atomicAdd(&h[v0 >> 6], 1); atomicAdd(&h[v1 >> 6], 1);
            atomicAdd(&h[v2 >> 6], 1); atomicAdd(&h[v3 >> 6], 1);
            atomicAdd(&deg[v0], 1); atomicAdd(&deg[v1], 1);
            atomicAdd(&deg[v2], 1); atomicAdd(&deg[v3], 1);
        } else {
            for (int j = e; j < EL; j++) {
                int v = base + rows[j];
                atomicAdd(&h[v >> 6], 1);
                atomicAdd(&deg[v], 1);
            }
        }
    }
}

__global__ void count_cvt_kernel(const float* __restrict__ u0, const float* __restrict__ i0,
                                 uchar_t* __restrict__ ub, uchar_t* __restrict__ ib,
                                 size_t n8u, size_t n8t,
                                 const int* __restrict__ sn_row, const int* __restrict__ ci_row,
                                 const int* __restrict__ ic_row, int* __restrict__ cntBlk,
                                 int* __restrict__ deg,
                                 int Es, int Eui, int Eiu, int U, int K) {
    __shared__ int h[KMAX];
    int b = blockIdx.x, tid = threadIdx.x;
    size_t gtid = (size_t)b * NTHR + tid;
    const size_t GT = (size_t)NBLK * NTHR;

    // fp8 conversion (independent of histogram)
    for (size_t i = gtid; i < n8t; i += GT) {
        const float4* src; uchar_t* dst; size_t di;
        if (i < n8u) { src = (const float4*)u0; dst = ub; di = i; }
        else         { src = (const float4*)i0; dst = ib; di = i - n8u; }
        float4 a = src[2 * di], c = src[2 * di + 1];
        int lo = 0, hi = 0;
        lo = __builtin_amdgcn_cvt_pk_fp8_f32(a.x * 256.0f, a.y * 256.0f, lo, false);
        lo = __builtin_amdgcn_cvt_pk_fp8_f32(a.z * 256.0f, a.w * 256.0f, lo, true);
        hi = __builtin_amdgcn_cvt_pk_fp8_f32(c.x * 256.0f, c.y * 256.0f, hi, false);
        hi = __builtin_amdgcn_cvt_pk_fp8_f32(c.z * 256.0f, c.w * 256.0f, hi, true);
        ((uint2*)dst)[di] = make_uint2((uint_t)lo, (uint_t)hi);
    }

    for (int i = tid; i < K; i += NTHR) h[i] = 0;
    __syncthreads();
    count_list(sn_row, Es, 0, h, deg, gtid, GT);
    count_list(ci_row, Eui, U, h, deg, gtid, GT);
    count_list(ic_row, Eiu, 2 * U, h, deg, gtid, GT);
    __syncthreads();
    for (int i = tid; i < K; i += NTHR) cntBlk[(size_t)b * K + i] = h[i];
}

// ---------------- pass 2a: within-segment prefix over blocks (parallel over 8 segments) -------

__global__ void base1_kernel(const int* __restrict__ cntBlk, int* __restrict__ baseBlk,
                             int* __restrict__ segsum, int K) {
    int k = blockIdx.x * 256 + threadIdx.x;
    int s = blockIdx.y;
    if (k >= K) return;
    int b0 = s * SEGW;
    int acc = 0;
    #pragma unroll 8
    for (int j = 0; j < SEGW; j++) {
        baseBlk[(size_t)(b0 + j) * K + k] = acc;
        acc += cntBlk[(size_t)(b0 + j) * K + k];
    }
    segsum[(size_t)s * K + k] = acc;
}

// ---------------- pass 2b: row-degree chunk scan (R5-verified) -------------------------------

__global__ void scan1_kernel(const int* __restrict__ deg, int* __restrict__ tmp,
                             int* __restrict__ bsum, int R) {
    __shared__ int sums[NTHR];
    int tid = threadIdx.x, b = blockIdx.x;
    int base0 = b * SCH + tid * 4;
    int loc[4];
    int s = 0;
    #pragma unroll
    for (int j = 0; j < 4; j++) {
        int idx = base0 + j;
        int v = (idx < R) ? deg[idx] : 0;
        loc[j] = s; s += v;
    }
    sums[tid] = s;
    __syncthreads();
    for (int off = 1; off < NTHR; off <<= 1) {
        int t = 0;
        if (tid >= off) t = sums[tid - off];
        __syncthreads();
        if (tid >= off) sums[tid] += t;
        __syncthreads();
    }
    int offs = (tid > 0) ? sums[tid - 1] : 0;
    #pragma unroll
    for (int j = 0; j < 4; j++) {
        int idx = base0 + j;
        if (idx < R) tmp[idx] = offs + loc[j];
    }
    if (tid == NTHR - 1) bsum[b] = sums[NTHR - 1];
}

// ---------------- pass 2c: add chunk offsets -> ptr ------------------------------------------

__global__ void ptr_kernel(const int* __restrict__ tmp, const int* __restrict__ bsum,
                           int* __restrict__ ptr, int R, int E) {
    __shared__ int soff;
    int b = blockIdx.x, tid = threadIdx.x;
    if (tid < 64) {
        int v = (tid < b) ? bsum[tid] : 0;
        #pragma unroll
        for (int o = 32; o > 0; o >>= 1) v += __shfl_xor(v, o, 64);
        if (tid == 0) soff = v;
    }
    __syncthreads();
    int off = soff;
    int base0 = b * SCH + tid * 4;
    #pragma unroll
    for (int j = 0; j < 4; j++) {
        int idx = base0 + j;
        if (idx < R) ptr[idx] = tmp[idx] + off;
    }
    if (b == 0 && tid == 0) ptr[R] = E;
}

// ---------------- pass 2d: segment prefixes + bucketPtr gather (parallel over k) --------------

__global__ void segoff_kernel(const int* __restrict__ segsum, const int* __restrict__ ptr,
                              int* __restrict__ segoff, int* __restrict__ bucketPtr, int K) {
    int k = blockIdx.x * 256 + threadIdx.x;
    if (k >= K) return;
    int tot = 0;
    #pragma unroll
    for (int sg = 0; sg < NSEG; sg++) {
        segoff[(size_t)sg * K + k] = tot;
        tot += segsum[(size_t)sg * K + k];
    }
    bucketPtr[k] = ptr[64 * k];
}

// ---------------- pass 3: place 8B records {row6<<26|col, bf16(t2)<<16|bf16(t1)} --------------
// t = exp(exp(sigmoid(raw*w+b))) in (2.72,15.2): softmax w/o max-sub is safe; LDS atomics only.
// cur[k] preloaded (coalesced): zero random gathers in per-edge store chain; block writes
// stay bucket-contiguous. R19: x4-vectorized edge reads, per-list hoisted weights.

__device__ __forceinline__ void place_edge(int v, int c, float r1, float r2,
                                           float w1, float b1, float w2, float b2,
                                           int* cur, uint2* __restrict__ barr) {
    float t1 = expf(expf(1.0f / (1.0f + expf(-(r1 * w1 + b1)))));
    float t2 = expf(expf(1.0f / (1.0f + expf(-(r2 * w2 + b2)))));
    uint_t packed = (uint_t)f2bf(t1) | ((uint_t)f2bf(t2) << 16);
    int pos = atomicAdd(&cur[v >> 6], 1);
    barr[pos] = make_uint2(((uint_t)(v & 63) << 26) | (uint_t)c, packed);
}

__device__ __forceinline__ void place_list(const int* __restrict__ rows, const int* __restrict__ cols,
                                           const float* __restrict__ x1, const float* __restrict__ x2,
                                           int EL, int base, float w1, float b1, float w2, float b2,
                                           int* cur, uint2* __restrict__ barr,
                                           size_t gtid, size_t GT) {
    size_t nq = ((size_t)EL + 3) >> 2;
    for (size_t q = gtid; q < nq; q += GT) {
        int e = (int)(q << 2);
        if (e + 4 <= EL) {
            int4 r4 = *(const int4*)(rows + e);
            int4 c4 = *(const int4*)(cols + e);
            float4 a4 = *(const float4*)(x1 + e);
            float4 b4 = *(const float4*)(x2 + e);
            place_edge(base + r4.x, c4.x, a4.x, b4.x, w1, b1, w2, b2, cur, barr);
            place_edge(base + r4.y, c4.y, a4.y, b4.y, w1, b1, w2, b2, cur, barr);
            place_edge(base + r4.z, c4.z, a4.z, b4.z, w1, b1, w2, b2, cur, barr);
            place_edge(base + r4.w, c4.w, a4.w, b4.w, w1, b1, w2, b2, cur, barr);
        } else {
            for (int j = e; j < EL; j++)
                place_edge(base + rows[j], cols[j], x1[j], x2[j], w1, b1, w2, b2, cur, barr);
        }
    }
}

__global__ void place_kernel(const int* __restrict__ sn_row, const int* __restrict__ sn_col,
                             const int* __restrict__ ci_row, const int* __restrict__ ci_col,
                             const int* __restrict__ ic_row, const int* __restrict__ ic_col,
                             const float* __restrict__ snii1, const float* __restrict__ snii2,
                             const float* __restrict__ ciii1, const float* __restrict__ ciii2,
                             const float* __restrict__ icii1, const float* __restrict__ icii2,
                             const float* __restrict__ lw, const float* __restrict__ lb,
                             const int* __restrict__ bucketPtr, const int* __restrict__ segoff,
                             const int* __restrict__ baseBlk, uint2* __restrict__ barr,
                             int Es, int Eui, int Eiu, int U, int K) {
    __shared__ int cur[KMAX];
    int b = blockIdx.x;
    int sb = b / SEGW;
    size_t gtid = (size_t)b * NTHR + threadIdx.x;
    const size_t GT = (size_t)NBLK * NTHR;
    for (int i = threadIdx.x; i < K; i += NTHR)
        cur[i] = bucketPtr[i] + segoff[(size_t)sb * K + i] + baseBlk[(size_t)b * K + i];
    __syncthreads();
    place_list(sn_row, sn_col, snii1, snii2, Es, 0,     lw[0], lb[0], lw[1], lb[1], cur, barr, gtid, GT);
    place_list(ci_row, ci_col, ciii1, ciii2, Eui, U,    lw[2], lb[2], lw[3], lb[3], cur, barr, gtid, GT);
    place_list(ic_row, ic_col, icii1, icii2, Eiu, 2 * U, lw[4], lb[4], lw[5], lb[5], cur, barr, gtid, GT);
}

// ---------------- pass 4: one block per bucket: single-pass scatter (ptr known) ---------------
// R19: histogram + wave-scan deleted; cur2 preloaded from ptr directly.

__global__ void finalize_kernel(const uint2* __restrict__ barr, const int* __restrict__ ptr,
                                uint2* __restrict__ rec, int R, int K) {
    __shared__ int cur2[64];
    int k = blockIdx.x;
    int r0 = k * 64;
    if (threadIdx.x < 64) {
        int r = r0 + threadIdx.x;
        cur2[threadIdx.x] = (r < R) ? ptr[r] : 0;
    }
    __syncthreads();
    int s0 = ptr[r0];
    int s1 = ptr[min(r0 + 64, R)];
    for (int e = s0 + (int)threadIdx.x; e < s1; e += (int)blockDim.x) {
        uint2 q = barr[e];
        int r6 = (int)(q.x >> 26);
        int pos = atomicAdd(&cur2[r6], 1);
        rec[pos] = make_uint2(q.x & 0x3ffffffu, q.y);
    }
}

// ---------------- layer kernels ----------------

__device__ __forceinline__ float att_scalar(float dot, float b1, float w2, float b2, float addc) {
    float h = tanhf(dot + b1);
    float z = h * w2 + b2;
    float lr = z > 0.0f ? z : 0.2f * z;   // leaky_relu alpha=0.2
    return expf(lr) + addc;
}

// packed fp8 -> float2 FMA: 4 cvt + 4 packed FMAs per 8 dims (v_pk_fma_f32)
__device__ __forceinline__ void fp8_fma8v(v2f acc[4], uint2 v, float a) {
    v2f av = {a, a};
    acc[0] += av * __builtin_amdgcn_cvt_pk_f32_fp8((int)v.x, false);
    acc[1] += av * __builtin_amdgcn_cvt_pk_f32_fp8((int)v.x, true);
    acc[2] += av * __builtin_amdgcn_cvt_pk_f32_fp8((int)v.y, false);
    acc[3] += av * __builtin_amdgcn_cvt_pk_f32_fp8((int)v.y, true);
}

__device__ __forceinline__ float dot8_lanes(float d) {
    #pragma unroll
    for (int off = 1; off < 8; off <<= 1) d += __shfl_xor(d, off, 64);
    return d;
}

// BRANCH-FREE batched CSR walk (R14). 8 lanes load 8 different records (coalesced),
// prefetch next batch via clamped load + cndmask. Padded records are (0,0): cx=0 is a
// valid row-0 gather and a=0 makes the FMA a no-op -> no divergent branches, 8
// independent gathers clustered per batch.
__device__ __forceinline__ void agg_row8(const uint2* __restrict__ rec, const uchar_t* __restrict__ tab,
                                         int e0, int e1, int l8, int lanebase,
                                         v2f acc[4], float& s) {
    if (e0 >= e1) return;
    int last = e1 - 1;
    int idx0 = e0 + l8;
    uint2 t0 = rec[min(idx0, last)];
    uint2 q;
    q.x = (idx0 <= last) ? t0.x : 0u;
    q.y = (idx0 <= last) ? t0.y : 0u;
    for (int base = e0; base < e1; base += 8) {
        int nidx = base + 8 + l8;
        uint2 tn = rec[min(nidx, last)];          // unconditional clamped prefetch
        uint2 qn;
        qn.x = (nidx <= last) ? tn.x : 0u;
        qn.y = (nidx <= last) ? tn.y : 0u;
        s += __uint_as_float(q.y << 16);          // per-lane partial of bf16 t1 (0 if padded)
        #pragma unroll
        for (int j = 0; j < 8; j++) {
            uint_t cx = __shfl(q.x, lanebase + j, 64);
            uint_t wy = __shfl(q.y, lanebase + j, 64);
            float a = __uint_as_float(wy << 16);
            uint2 v = ((const uint2*)(tab + (size_t)cx * DIM))[l8];
            fp8_fma8v(acc, v, a);
        }
        q = qn;
    }
}

// one row per 8-lane group; 256-thr blocks (R6 lesson: 1024-thr blocks -> 41% occupancy).
__global__ void layer1_kernel(const uchar_t* __restrict__ ub8, const uchar_t* __restrict__ ib8,
                              const float* __restrict__ u0, const float* __restrict__ i0,
                              const int* __restrict__ ptr, const uint2* __restrict__ rec,
                              const float* __restrict__ W1, const float* __restrict__ b1v,
                              const float* __restrict__ w2v, const float* __restrict__ b2v,
                              float* __restrict__ u1, float* __restrict__ i1, int U, int I) {
    int gid = blockIdx.x * (blockDim.x >> 3) + (threadIdx.x >> 3);
    int lane = threadIdx.x & 63;
    int l8 = lane & 7;
    int lanebase = lane & 56;
    if (gid >= U + I) return;
    bool is_user = gid < U;
    int r = is_user ? gid : gid - U;

    v2f A[4]  = {{0.f, 0.f}, {0.f, 0.f}, {0.f, 0.f}, {0.f, 0.f}};
    v2f Bv[4] = {{0.f, 0.f}, {0.f, 0.f}, {0.f, 0.f}, {0.f, 0.f}};
    float s_a = 0.f, s_b = 0.f;

    if (is_user) {
        agg_row8(rec, ib8, ptr[U + r], ptr[U + r + 1], l8, lanebase, A, s_a);   // u_from_i (ci)
        agg_row8(rec, ub8, ptr[r], ptr[r + 1], l8, lanebase, Bv, s_b);          // u_from_u (sn)
    } else {
        agg_row8(rec, ub8, ptr[2 * U + r], ptr[2 * U + r + 1], l8, lanebase, A, s_a);  // i_from_u (ic)
    }
    s_a = dot8_lanes(s_a);
    s_b = dot8_lanes(s_b);

    float ka = (1.0f / (s_a + 1e-12f)) * 0.00390625f;   // softmax denom * fp8 scale
    float kb = (1.0f / (s_b + 1e-12f)) * 0.00390625f;
    float ac[8], bc[8];
    #pragma unroll
    for (int j = 0; j < 4; j++) {
        ac[2 * j] = A[j][0] * ka;  ac[2 * j + 1] = A[j][1] * ka;
        bc[2 * j] = Bv[j][0] * kb; bc[2 * j + 1] = Bv[j][1] * kb;
    }

    const float* selfp = (is_user ? u0 : i0) + (size_t)r * DIM + 8 * l8;
    float4 s0 = *(const float4*)selfp;
    float4 s1 = *(const float4*)(selfp + 4);
    float sf[8] = {s0.x, s0.y, s0.z, s0.w, s1.x, s1.y, s1.z, s1.w};
    int k = is_user ? 0 : 4;
    const float* Wa = W1 + k * 2 * DIM;
    const float* Wb = Wa + 2 * DIM;
    float d1 = 0.f, d2 = 0.f;
    #pragma unroll
    for (int j = 0; j < 8; j++) {
        float wa0 = Wa[8 * l8 + j], wa1 = Wa[DIM + 8 * l8 + j];
        float wb0 = Wb[8 * l8 + j], wb1 = Wb[DIM + 8 * l8 + j];
        if (is_user) {
            d1 += sf[j] * wa0 + ac[j] * wa1;
            d2 += sf[j] * wb0 + bc[j] * wb1;
        } else {
            d1 += sf[j] * (wa0 + wa1);                 // concat([it, it])
            d2 += sf[j] * wb0 + ac[j] * wb1;
        }
    }
    d1 = dot8_lanes(d1);
    d2 = dot8_lanes(d2);

    float out8[8];
    float* op;
    if (is_user) {
        float a_int = att_scalar(d1, b1v[0], w2v[0], b2v[0], 0.7f);
        float a_soc = att_scalar(d2, b1v[1], w2v[1], b2v[1], 0.3f);
        float sg = a_int + a_soc;
        float wi = a_int / sg, ws = a_soc / sg;
        #pragma unroll
        for (int j = 0; j < 8; j++)
            out8[j] = 0.5f * sf[j] + 0.5f * (wi * ac[j] + ws * bc[j]);
        op = u1 + (size_t)r * DIM + 8 * l8;
    } else {
        float a_self = att_scalar(d1, b1v[4], w2v[4], b2v[4], 1.0f);
        float a_cust = att_scalar(d2, b1v[5], w2v[5], b2v[5], 1.0f);
        float sg = a_self + a_cust;
        float wi = a_self / sg, ws = a_cust / sg;
        #pragma unroll
        for (int j = 0; j < 8; j++)
            out8[j] = wi * sf[j] + ws * ac[j];
        op = i1 + (size_t)r * DIM + 8 * l8;
    }
    *(float4*)op = make_float4(out8[0], out8[1], out8[2], out8[3]);
    *(float4*)(op + 4) = make_float4(out8[4], out8[5], out8[6], out8[7]);
}

__global__ void layer2_kernel(const float* __restrict__ u1, const float* __restrict__ i1,
                              const int* __restrict__ ptr, const uint2* __restrict__ rec,
                              const float* __restrict__ W1, const float* __restrict__ b1v,
                              const float* __restrict__ w2v, const float* __restrict__ b2v,
                              const int* __restrict__ uidx, const int* __restrict__ iidx,
                              float* __restrict__ u2s, float* __restrict__ i2s, int U, int B) {
    int wid = blockIdx.x * (blockDim.x >> 6) + (threadIdx.x >> 6);
    int lane = threadIdx.x & 63;
    if (wid >= 2 * B) return;
    int g = lane >> 3, l8 = lane & 7;
    bool is_user = wid < B;
    int b = is_user ? wid : wid - B;
    int r = is_user ? uidx[b] : iidx[b];

    float acc_a[8] = {0, 0, 0, 0, 0, 0, 0, 0};
    float acc_b[8] = {0, 0, 0, 0, 0, 0, 0, 0};
    float s_a = 0.f, s_b = 0.f;

    if (is_user) {
        int e0 = ptr[U + r], e1 = ptr[U + r + 1];
        for (int e = e0 + g; e < e1; e += 8) {
            uint2 q = rec[e];
            float a = __uint_as_float(q.y & 0xffff0000u);  // bf16 t2
            s_a += a;
            const float4* rp = (const float4*)(i1 + (size_t)q.x * DIM);
            float4 v0 = rp[2 * l8], v1 = rp[2 * l8 + 1];
            acc_a[0] = fmaf(a, v0.x, acc_a[0]); acc_a[1] = fmaf(a, v0.y, acc_a[1]);
            acc_a[2] = fmaf(a, v0.z, acc_a[2]); acc_a[3] = fmaf(a, v0.w, acc_a[3]);
            acc_a[4] = fmaf(a, v1.x, acc_a[4]); acc_a[5] = fmaf(a, v1.y, acc_a[5]);
            acc_a[6] = fmaf(a, v1.z, acc_a[6]); acc_a[7] = fmaf(a, v1.w, acc_a[7]);
        }
        e0 = ptr[r]; e1 = ptr[r + 1];
        for (int e = e0 + g; e < e1; e += 8) {
            uint2 q = rec[e];
            float a = __uint_as_float(q.y & 0xffff0000u);
            s_b += a;
            const float4* rp = (const float4*)(u1 + (size_t)q.x * DIM);
            float4 v0 = rp[2 * l8], v1 = rp[2 * l8 + 1];
            acc_b[0] = fmaf(a, v0.x, acc_b[0]); acc_b[1] = fmaf(a, v0.y, acc_b[1]);
            acc_b[2] = fmaf(a, v0.z, acc_b[2]); acc_b[3] = fmaf(a, v0.w, acc_b[3]);
            acc_b[4] = fmaf(a, v1.x, acc_b[4]); acc_b[5] = fmaf(a, v1.y, acc_b[5]);
            acc_b[6] = fmaf(a, v1.z, acc_b[6]); acc_b[7] = fmaf(a, v1.w, acc_b[7]);
        }
    } else {
        int e0 = ptr[2 * U + r], e1 = ptr[2 * U + r + 1];
        for (int e = e0 + g; e < e1; e += 8) {
            uint2 q = rec[e];
            float a = __uint_as_float(q.y & 0xffff0000u);
            s_a += a;
            const float4* rp = (const float4*)(u1 + (size_t)q.x * DIM);
            float4 v0 = rp[2 * l8], v1 = rp[2 * l8 + 1];
            acc_a[0] = fmaf(a, v0.x, acc_a[0]); acc_a[1] = fmaf(a, v0.y, acc_a[1]);
            acc_a[2] = fmaf(a, v0.z, acc_a[2]); acc_a[3] = fmaf(a, v0.w, acc_a[3]);
            acc_a[4] = fmaf(a, v1.x, acc_a[4]); acc_a[5] = fmaf(a, v1.y, acc_a[5]);
            acc_a[6] = fmaf(a, v1.z, acc_a[6]); acc_a[7] = fmaf(a, v1.w, acc_a[7]);
        }
    }

    #pragma unroll
    for (int off = 8; off < 64; off <<= 1) {
        s_a += __shfl_xor(s_a, off, 64);
        #pragma unroll
        for (int j = 0; j < 8; j++) acc_a[j] += __shfl_xor(acc_a[j], off, 64);
    }
    if (is_user) {
        #pragma unroll
        for (int off = 8; off < 64; off <<= 1) {
            s_b += __shfl_xor(s_b, off, 64);
            #pragma unroll
            for (int j = 0; j < 8; j++) acc_b[j] += __shfl_xor(acc_b[j], off, 64);
        }
    }
    float ka = 1.0f / (s_a + 1e-12f);
    float kb = 1.0f / (s_b + 1e-12f);

    if (g == 0) {
        #pragma unroll
        for (int j = 0; j < 8; j++) { acc_a[j] *= ka; acc_b[j] *= kb; }
        const float* selfp = (is_user ? u1 : i1) + (size_t)r * DIM + 8 * l8;
        float4 s0 = *(const float4*)selfp;
        float4 s1 = *(const float4*)(selfp + 4);
        float sf[8] = {s0.x, s0.y, s0.z, s0.w, s1.x, s1.y, s1.z, s1.w};
        int k = is_user ? 2 : 6;
        const float* Wa = W1 + k * 2 * DIM;
        const float* Wb = Wa + 2 * DIM;
        float d1 = 0.f, d2 = 0.f;
        #pragma unroll
        for (int j = 0; j < 8; j++) {
            float wa0 = Wa[8 * l8 + j], wa1 = Wa[DIM + 8 * l8 + j];
            float wb0 = Wb[8 * l8 + j], wb1 = Wb[DIM + 8 * l8 + j];
            if (is_user) {
                d1 += sf[j] * wa0 + acc_a[j] * wa1;
                d2 += sf[j] * wb0 + acc_b[j] * wb1;
            } else {
                d1 += sf[j] * (wa0 + wa1);
                d2 += sf[j] * wb0 + acc_a[j] * wb1;
            }
        }
        d1 = dot8_lanes(d1);
        d2 = dot8_lanes(d2);

        float out8[8];
        float* op;
        if (is_user) {
            float a_int = att_scalar(d1, b1v[2], w2v[2], b2v[2], 0.7f);
            float a_soc = att_scalar(d2, b1v[3], w2v[3], b2v[3], 0.3f);
            float sg = a_int + a_soc;
            float wi = a_int / sg, ws = a_soc / sg;
            #pragma unroll
            for (int j = 0; j < 8; j++)
                out8[j] = 0.5f * sf[j] + 0.5f * (wi * acc_a[j] + ws * acc_b[j]);
            op = u2s + (size_t)b * DIM + 8 * l8;
        } else {
            float a_self = att_scalar(d1, b1v[6], w2v[6], b2v[6], 1.0f);
            float a_cust = att_scalar(d2, b1v[7], w2v[7], b2v[7], 1.0f);
            float sg = a_self + a_cust;
            float wi = a_self / sg, ws = a_cust / sg;
            #pragma unroll
            for (int j = 0; j < 8; j++)
                out8[j] = wi * sf[j] + ws * acc_a[j];
            op = i2s + (size_t)b * DIM + 8 * l8;
        }
        *(float4*)op = make_float4(out8[0], out8[1], out8[2], out8[3]);
        *(float4*)(op + 4) = make_float4(out8[4], out8[5], out8[6], out8[7]);
    }
}

// ---------------- final: sigmoid(dot over [u0|u1|u2] . [i0|i1|i2]) ----------------

__global__ void final_kernel(const float* __restrict__ u0, const float* __restrict__ u1,
                             const float* __restrict__ u2s,
                             const float* __restrict__ i0, const float* __restrict__ i1,
                             const float* __restrict__ i2s,
                             const int* __restrict__ uidx, const int* __restrict__ iidx,
                             float* __restrict__ out, int n) {
    int b = blockIdx.x * (blockDim.x >> 6) + (threadIdx.x >> 6);
    int lane = threadIdx.x & 63;
    if (b >= n) return;
    size_t ur = (size_t)uidx[b] * DIM + lane;
    size_t ir = (size_t)iidx[b] * DIM + lane;
    size_t sr = (size_t)b * DIM + lane;
    float acc = u0[ur] * i0[ir] + u1[ur] * i1[ir] + u2s[sr] * i2s[sr];
    #pragma unroll
    for (int off = 32; off > 0; off >>= 1) acc += __shfl_xor(acc, off, 64);
    if (lane == 0) out[b] = 1.0f / (1.0f + expf(-acc));
}

// ---------------- launch ----------------

extern "C" void kernel_launch(void* const* d_in, const int* in_sizes, int n_in,
                              void* d_out, int out_size, void* d_ws, size_t ws_size,
                              hipStream_t stream) {
    const float* user_emb = (const float*)d_in[0];
    const float* item_emb = (const float*)d_in[1];
    const float* snii1 = (const float*)d_in[2];
    const float* snii2 = (const float*)d_in[3];
    const float* ciii1 = (const float*)d_in[4];
    const float* ciii2 = (const float*)d_in[5];
    const float* icii1 = (const float*)d_in[6];
    const float* icii2 = (const float*)d_in[7];
    const float* low_w = (const float*)d_in[8];
    const float* low_b = (const float*)d_in[9];
    const float* att1_W = (const float*)d_in[10];
    const float* att1_b = (const float*)d_in[11];
    const float* att2_w = (const float*)d_in[12];
    const float* att2_b = (const float*)d_in[13];
    const int* sn_row = (const int*)d_in[14];
    const int* sn_col = (const int*)d_in[15];
    const int* ci_row = (const int*)d_in[16];
    const int* ci_col = (const int*)d_in[17];
    const int* ic_row = (const int*)d_in[18];
    const int* ic_col = (const int*)d_in[19];
    const int* user_idx = (const int*)d_in[20];
    const int* item_idx = (const int*)d_in[21];
    float* out = (float*)d_out;

    const int Es  = in_sizes[2];
    const int Eui = in_sizes[4];
    const int Eiu = in_sizes[6];
    const int U = in_sizes[0] / DIM;
    const int I = in_sizes[1] / DIM;
    const int B = in_sizes[20];
    const int R = 2 * U + I;                // virtual rows: [0,U)=sn, [U,2U)=ci, [2U,2U+I)=ic
    const int E = Es + Eui + Eiu;
    const int K = (R + 63) >> 6;            // 64-row buckets; 3907 <= KMAX
    const int NCH = (R + SCH - 1) / SCH;    // scan chunks; 62 <= 64 (wave-reduce limit)

    // ---- workspace carve (4-byte units, 16B-aligned) ----
    char* wsb = (char*)d_ws;
    size_t off = 0;
    auto alloc = [&](size_t n_units) {
        off = (off + 3) & ~(size_t)3;
        void* p = wsb + off * 4; off += n_units; return p;
    };

    int* cntBlk    = (int*)alloc((size_t)NBLK * K);
    int* baseBlk   = (int*)alloc((size_t)NBLK * K);
    int* segsum    = (int*)alloc((size_t)NSEG * K);
    int* segoff    = (int*)alloc((size_t)NSEG * K);
    int* bucketPtr = (int*)alloc(K);
    int* deg       = (int*)alloc(R);
    int* tmp       = (int*)alloc(R);
    int* bsum      = (int*)alloc(64);
    int* ptr       = (int*)alloc(R + 1);
    uint2* barr    = (uint2*)alloc((size_t)E * 2);
    uint2* rec     = (uint2*)alloc((size_t)E * 2);
    uchar_t* ub8 = (uchar_t*)alloc((size_t)U * DIM / 4);
    uchar_t* ib8 = (uchar_t*)alloc((size_t)I * DIM / 4);
    float* u1  = (float*)alloc((size_t)U * DIM);
    float* i1  = (float*)alloc((size_t)I * DIM);
    float* u2s = (float*)alloc((size_t)B * DIM);
    float* i2s = (float*)alloc((size_t)B * DIM);
    (void)ws_size;

    size_t n8u = (size_t)U * DIM / 8, n8t = (size_t)(U + I) * DIM / 8;

    // ---- CSR build: memset | cvt+count | base1 | scan1 | ptr | segoff | place | finalize ----
    hipMemsetAsync(deg, 0, sizeof(int) * (size_t)R, stream);
    count_cvt_kernel<<<NBLK, NTHR, 0, stream>>>(user_emb, item_emb, ub8, ib8, n8u, n8t,
                                                sn_row, ci_row, ic_row, cntBlk, deg,
                                                Es, Eui, Eiu, U, K);
    base1_kernel<<<dim3((K + 255) / 256, NSEG), 256, 0, stream>>>(cntBlk, baseBlk, segsum, K);
    scan1_kernel<<<NCH, NTHR, 0, stream>>>(deg, tmp, bsum, R);
    ptr_kernel<<<NCH, NTHR, 0, stream>>>(tmp, bsum, ptr, R, E);
    segoff_kernel<<<(K + 255) / 256, 256, 0, stream>>>(segsum, ptr, segoff, bucketPtr, K);
    place_kernel<<<NBLK, NTHR, 0, stream>>>(sn_row, sn_col, ci_row, ci_col, ic_row, ic_col,
                                            snii1, snii2, ciii1, ciii2, icii1, icii2,
                                            low_w, low_b, bucketPtr, segoff, baseBlk, barr,
                                            Es, Eui, Eiu, U, K);
    finalize_kernel<<<K, 256, 0, stream>>>(barr, ptr, rec, R, K);

    // ---- layer 1: one row per 8-lane group, 32 rows per 256-thr block ----
    layer1_kernel<<<(U + I + 31) / 32, 256, 0, stream>>>(ub8, ib8, user_emb, item_emb,
        ptr, rec, att1_W, att1_b, att2_w, att2_b, u1, i1, U, I);

    // ---- layer 2 (merged, sampled rows only) ----
    layer2_kernel<<<(2 * B + 3) / 4, 256, 0, stream>>>(u1, i1, ptr, rec,
        att1_W, att1_b, att2_w, att2_b, user_idx, item_idx, u2s, i2s, U, B);

    // ---- final gather-dot-sigmoid ----
    final_kernel<<<(B + 3) / 4, 256, 0, stream>>>(user_emb, u1, u2s, item_emb, i1, i2s,
                                                  user_idx, item_idx, out, B);
}

// Round 9
// 376.439 us; speedup vs baseline: 1.1169x; 1.1169x over previous
//
#include <hip/hip_runtime.h>
#include <math.h>

#define DIM 64
#define NBLK_P 64        // blocks in count/place. R9: FEW blocks -> ~11 rec (88B) per
                         // (block,bucket) -> near-full 64B lines on barr writes.
                         // R3 PMC: place @NBLK512 wrote 74MB for 22.4MB payload (3.3x amp)
                         // and was exactly BW-bound at 1.33TB/s.
#define NTHR 1024
#define KMAX 4096        // max buckets; K = ceil((2U+I)/64) = 3907

// LESSONS (PMC-verified): R5/R8 — global atomics & scattered 8B stores are memory-side,
// line-granular HBM round-trips on gfx950 (WRITE_SIZE 74->176MB / +86MB). Atomics: LDS only.

typedef unsigned short ushort_t;
typedef unsigned int uint_t;
typedef unsigned char uchar_t;
typedef float v2f __attribute__((ext_vector_type(2)));

__device__ __forceinline__ ushort_t f2bf(float f) {
    uint_t u = __float_as_uint(f);
    return (ushort_t)((u + 0x7fffu + ((u >> 16) & 1u)) >> 16);
}

// ---------------- pass 1: per-(block,bucket) counts (LDS histogram only) ----------------

__global__ void count_kernel(const int* __restrict__ sn_row, const int* __restrict__ ci_row,
                             const int* __restrict__ ic_row, int* __restrict__ cntBlk,
                             int Es, int Eui, int Eiu, int U, int K) {
    __shared__ int h[KMAX];
    int b = blockIdx.x, tid = threadIdx.x;
    int E = Es + Eui + Eiu;
    int per = (E + NBLK_P - 1) / NBLK_P;
    int e0 = b * per, e1 = min(e0 + per, E);
    for (int i = tid; i < K; i += NTHR) h[i] = 0;
    __syncthreads();
    for (int e = e0 + tid; e < e1; e += NTHR) {
        int r;
        if (e < Es) r = sn_row[e];
        else if (e < Es + Eui) r = U + ci_row[e - Es];
        else r = 2 * U + ic_row[e - Es - Eui];
        atomicAdd(&h[r >> 6], 1);
    }
    __syncthreads();
    for (int i = tid; i < K; i += NTHR) cntBlk[(size_t)b * K + i] = h[i];
}

// ---------------- pass 2: per-bucket prefix over 64 blocks (coalesced across threads) --------

__global__ void base_kernel(const int* __restrict__ cntBlk, int* __restrict__ baseBlk,
                            int* __restrict__ total, int K) {
    int k = blockIdx.x * blockDim.x + threadIdx.x;
    if (k >= K) return;
    int s = 0;
    #pragma unroll 8
    for (int b = 0; b < NBLK_P; b++) {
        baseBlk[(size_t)b * K + k] = s;
        s += cntBlk[(size_t)b * K + k];
    }
    total[k] = s;
}

// ---------------- pass 3: single-block exclusive scan of bucket totals (K <= 4096) ----------

__global__ void scan_kernel(const int* __restrict__ total, int* __restrict__ bucketPtr,
                            int K, int E) {
    __shared__ int sums[NTHR];
    int tid = threadIdx.x;
    const int CH = KMAX / NTHR;           // 4
    int loc[CH];
    int base0 = tid * CH, s = 0;
    #pragma unroll
    for (int j = 0; j < CH; j++) {
        int idx = base0 + j;
        int v = (idx < K) ? total[idx] : 0;
        loc[j] = s; s += v;
    }
    sums[tid] = s;
    __syncthreads();
    for (int off = 1; off < NTHR; off <<= 1) {
        int t = 0;
        if (tid >= off) t = sums[tid - off];
        __syncthreads();
        if (tid >= off) sums[tid] += t;
        __syncthreads();
    }
    int offs = (tid > 0) ? sums[tid - 1] : 0;
    #pragma unroll
    for (int j = 0; j < CH; j++) {
        int idx = base0 + j;
        if (idx < K) bucketPtr[idx] = offs + loc[j];
    }
    if (tid == 0) bucketPtr[K] = E;
}

// ---------------- pass 4: place 8B records {row6<<26|col, bf16(t2)<<16|bf16(t1)} ------------
// t = exp(exp(sigmoid(raw*w+b))) in (2.72,15.2): softmax w/o max-sub is safe; LDS atomics only.
// cur[k] preloaded with bucketPtr[k]+baseBlk[b][k] (coalesced): zero random gathers in the
// per-edge store chain; with NBLK_P=64 each block's per-bucket run is ~88B -> full lines.

__global__ void place_kernel(const int* __restrict__ sn_row, const int* __restrict__ sn_col,
                             const int* __restrict__ ci_row, const int* __restrict__ ci_col,
                             const int* __restrict__ ic_row, const int* __restrict__ ic_col,
                             const float* __restrict__ snii1, const float* __restrict__ snii2,
                             const float* __restrict__ ciii1, const float* __restrict__ ciii2,
                             const float* __restrict__ icii1, const float* __restrict__ icii2,
                             const float* __restrict__ lw, const float* __restrict__ lb,
                             const int* __restrict__ bucketPtr, const int* __restrict__ baseBlk,
                             uint2* __restrict__ barr,
                             int Es, int Eui, int Eiu, int U, int K) {
    __shared__ int cur[KMAX];
    int E = Es + Eui + Eiu;
    int per = (E + NBLK_P - 1) / NBLK_P;
    int b = blockIdx.x;
    int e0 = b * per, e1 = min(e0 + per, E);
    for (int i = threadIdx.x; i < K; i += NTHR)
        cur[i] = bucketPtr[i] + baseBlk[(size_t)b * K + i];
    __syncthreads();
    for (int e = e0 + threadIdx.x; e < e1; e += NTHR) {
        int r, c, j1, j2;
        float r1, r2;
        if (e < Es) {
            r = sn_row[e]; c = sn_col[e]; r1 = snii1[e]; r2 = snii2[e]; j1 = 0; j2 = 1;
        } else if (e < Es + Eui) {
            int t = e - Es;
            r = U + ci_row[t]; c = ci_col[t]; r1 = ciii1[t]; r2 = ciii2[t]; j1 = 2; j2 = 3;
        } else {
            int t = e - Es - Eui;
            r = 2 * U + ic_row[t]; c = ic_col[t]; r1 = icii1[t]; r2 = icii2[t]; j1 = 4; j2 = 5;
        }
        float t1 = expf(expf(1.0f / (1.0f + expf(-(r1 * lw[j1] + lb[j1])))));
        float t2 = expf(expf(1.0f / (1.0f + expf(-(r2 * lw[j2] + lb[j2])))));
        uint_t packed = (uint_t)f2bf(t1) | ((uint_t)f2bf(t2) << 16);
        int k = r >> 6;
        int pos = atomicAdd(&cur[k], 1);
        barr[pos] = make_uint2(((uint_t)(r & 63) << 26) | (uint_t)c, packed);
    }
}

// ---------------- pass 5: one block per bucket: row ptrs + CSR-ordered rec; + fp8 cvt --------
// R9: fp8 conversion moved here (grid = K blocks = plenty of parallelism to stream 48MB;
// the 64-block count/place grids couldn't). ub8/ib8 are only needed by layer1 (later).

__global__ void finalize_kernel(const float* __restrict__ u0f, const float* __restrict__ i0f,
                                uchar_t* __restrict__ ub, uchar_t* __restrict__ ib,
                                size_t n8u, size_t n8t,
                                const uint2* __restrict__ barr, const int* __restrict__ bucketPtr,
                                int* __restrict__ ptr, uint2* __restrict__ rec,
                                int R, int K, int E) {
    // fp8 cvt prologue (emb ~N(0,0.01^2) x256 in e4m3 normal range; verified absmax 0.0)
    size_t gt = (size_t)blockIdx.x * blockDim.x + threadIdx.x;
    size_t GT = (size_t)gridDim.x * blockDim.x;
    for (size_t i = gt; i < n8t; i += GT) {
        const float4* src; uchar_t* dst; size_t di;
        if (i < n8u) { src = (const float4*)u0f; dst = ub; di = i; }
        else         { src = (const float4*)i0f; dst = ib; di = i - n8u; }
        float4 a = src[2 * di], c = src[2 * di + 1];
        int lo = 0, hi = 0;
        lo = __builtin_amdgcn_cvt_pk_fp8_f32(a.x * 256.0f, a.y * 256.0f, lo, false);
        lo = __builtin_amdgcn_cvt_pk_fp8_f32(a.z * 256.0f, a.w * 256.0f, lo, true);
        hi = __builtin_amdgcn_cvt_pk_fp8_f32(c.x * 256.0f, c.y * 256.0f, hi, false);
        hi = __builtin_amdgcn_cvt_pk_fp8_f32(c.z * 256.0f, c.w * 256.0f, hi, true);
        ((uint2*)dst)[di] = make_uint2((uint_t)lo, (uint_t)hi);
    }

    __shared__ int h[64], sc[64], cur2[64];
    int k = blockIdx.x;
    int s0 = bucketPtr[k], s1 = bucketPtr[k + 1];
    if (threadIdx.x < 64) { h[threadIdx.x] = 0; cur2[threadIdx.x] = 0; }
    __syncthreads();
    for (int e = s0 + (int)threadIdx.x; e < s1; e += (int)blockDim.x)
        atomicAdd(&h[(int)(barr[e].x >> 26)], 1);
    __syncthreads();
    if (threadIdx.x < 64) {
        int v = h[threadIdx.x];
        int inc = v;
        #pragma unroll
        for (int off = 1; off < 64; off <<= 1) {
            int t = __shfl_up(inc, off, 64);
            if ((int)threadIdx.x >= off) inc += t;
        }
        sc[threadIdx.x] = inc - v;                 // exclusive prefix
        int r = k * 64 + (int)threadIdx.x;
        if (r < R) ptr[r] = s0 + inc - v;
    }
    if (k == K - 1 && threadIdx.x == 0) ptr[R] = E;
    __syncthreads();
    for (int e = s0 + (int)threadIdx.x; e < s1; e += (int)blockDim.x) {
        uint2 q = barr[e];
        int r6 = (int)(q.x >> 26);
        int rank = atomicAdd(&cur2[r6], 1);
        rec[s0 + sc[r6] + rank] = make_uint2(q.x & 0x3ffffffu, q.y);
    }
}

// ---------------- layer kernels ----------------

__device__ __forceinline__ float att_scalar(float dot, float b1, float w2, float b2, float addc) {
    float h = tanhf(dot + b1);
    float z = h * w2 + b2;
    float lr = z > 0.0f ? z : 0.2f * z;   // leaky_relu alpha=0.2
    return expf(lr) + addc;
}

// packed fp8 -> float2 FMA: 4 cvt + 4 packed FMAs per 8 dims (v_pk_fma_f32)
__device__ __forceinline__ void fp8_fma8v(v2f acc[4], uint2 v, float a) {
    v2f av = {a, a};
    acc[0] += av * __builtin_amdgcn_cvt_pk_f32_fp8((int)v.x, false);
    acc[1] += av * __builtin_amdgcn_cvt_pk_f32_fp8((int)v.x, true);
    acc[2] += av * __builtin_amdgcn_cvt_pk_f32_fp8((int)v.y, false);
    acc[3] += av * __builtin_amdgcn_cvt_pk_f32_fp8((int)v.y, true);
}

__device__ __forceinline__ float dot8_lanes(float d) {
    #pragma unroll
    for (int off = 1; off < 8; off <<= 1) d += __shfl_xor(d, off, 64);
    return d;
}

// BRANCH-FREE batched CSR walk (R14). 8 lanes load 8 different records (coalesced),
// prefetch next batch via clamped load + cndmask. Padded records are (0,0): cx=0 is a
// valid row-0 gather and a=0 makes the FMA a no-op -> no divergent branches, 8
// independent gathers clustered per batch.
__device__ __forceinline__ void agg_row8(const uint2* __restrict__ rec, const uchar_t* __restrict__ tab,
                                         int e0, int e1, int l8, int lanebase,
                                         v2f acc[4], float& s) {
    if (e0 >= e1) return;
    int last = e1 - 1;
    int idx0 = e0 + l8;
    uint2 t0 = rec[min(idx0, last)];
    uint2 q;
    q.x = (idx0 <= last) ? t0.x : 0u;
    q.y = (idx0 <= last) ? t0.y : 0u;
    for (int base = e0; base < e1; base += 8) {
        int nidx = base + 8 + l8;
        uint2 tn = rec[min(nidx, last)];          // unconditional clamped prefetch
        uint2 qn;
        qn.x = (nidx <= last) ? tn.x : 0u;
        qn.y = (nidx <= last) ? tn.y : 0u;
        s += __uint_as_float(q.y << 16);          // per-lane partial of bf16 t1 (0 if padded)
        #pragma unroll
        for (int j = 0; j < 8; j++) {
            uint_t cx = __shfl(q.x, lanebase + j, 64);
            uint_t wy = __shfl(q.y, lanebase + j, 64);
            float a = __uint_as_float(wy << 16);
            uint2 v = ((const uint2*)(tab + (size_t)cx * DIM))[l8];
            fp8_fma8v(acc, v, a);
        }
        q = qn;
    }
}

// one row per 8-lane group; 256-thr blocks (R6 lesson: 1024-thr blocks -> 41% occupancy).
__global__ void layer1_kernel(const uchar_t* __restrict__ ub8, const uchar_t* __restrict__ ib8,
                              const float* __restrict__ u0, const float* __restrict__ i0,
                              const int* __restrict__ ptr, const uint2* __restrict__ rec,
                              const float* __restrict__ W1, const float* __restrict__ b1v,
                              const float* __restrict__ w2v, const float* __restrict__ b2v,
                              float* __restrict__ u1, float* __restrict__ i1, int U, int I) {
    int gid = blockIdx.x * (blockDim.x >> 3) + (threadIdx.x >> 3);
    int lane = threadIdx.x & 63;
    int l8 = lane & 7;
    int lanebase = lane & 56;
    if (gid >= U + I) return;
    bool is_user = gid < U;
    int r = is_user ? gid : gid - U;

    v2f A[4]  = {{0.f, 0.f}, {0.f, 0.f}, {0.f, 0.f}, {0.f, 0.f}};
    v2f Bv[4] = {{0.f, 0.f}, {0.f, 0.f}, {0.f, 0.f}, {0.f, 0.f}};
    float s_a = 0.f, s_b = 0.f;

    if (is_user) {
        agg_row8(rec, ib8, ptr[U + r], ptr[U + r + 1], l8, lanebase, A, s_a);   // u_from_i (ci)
        agg_row8(rec, ub8, ptr[r], ptr[r + 1], l8, lanebase, Bv, s_b);          // u_from_u (sn)
    } else {
        agg_row8(rec, ub8, ptr[2 * U + r], ptr[2 * U + r + 1], l8, lanebase, A, s_a);  // i_from_u (ic)
    }
    s_a = dot8_lanes(s_a);
    s_b = dot8_lanes(s_b);

    float ka = (1.0f / (s_a + 1e-12f)) * 0.00390625f;   // softmax denom * fp8 scale
    float kb = (1.0f / (s_b + 1e-12f)) * 0.00390625f;
    float ac[8], bc[8];
    #pragma unroll
    for (int j = 0; j < 4; j++) {
        ac[2 * j] = A[j][0] * ka;  ac[2 * j + 1] = A[j][1] * ka;
        bc[2 * j] = Bv[j][0] * kb; bc[2 * j + 1] = Bv[j][1] * kb;
    }

    const float* selfp = (is_user ? u0 : i0) + (size_t)r * DIM + 8 * l8;
    float4 s0 = *(const float4*)selfp;
    float4 s1 = *(const float4*)(selfp + 4);
    float sf[8] = {s0.x, s0.y, s0.z, s0.w, s1.x, s1.y, s1.z, s1.w};
    int k = is_user ? 0 : 4;
    const float* Wa = W1 + k * 2 * DIM;
    const float* Wb = Wa + 2 * DIM;
    float d1 = 0.f, d2 = 0.f;
    #pragma unroll
    for (int j = 0; j < 8; j++) {
        float wa0 = Wa[8 * l8 + j], wa1 = Wa[DIM + 8 * l8 + j];
        float wb0 = Wb[8 * l8 + j], wb1 = Wb[DIM + 8 * l8 + j];
        if (is_user) {
            d1 += sf[j] * wa0 + ac[j] * wa1;
            d2 += sf[j] * wb0 + bc[j] * wb1;
        } else {
            d1 += sf[j] * (wa0 + wa1);                 // concat([it, it])
            d2 += sf[j] * wb0 + ac[j] * wb1;
        }
    }
    d1 = dot8_lanes(d1);
    d2 = dot8_lanes(d2);

    float out8[8];
    float* op;
    if (is_user) {
        float a_int = att_scalar(d1, b1v[0], w2v[0], b2v[0], 0.7f);
        float a_soc = att_scalar(d2, b1v[1], w2v[1], b2v[1], 0.3f);
        float sg = a_int + a_soc;
        float wi = a_int / sg, ws = a_soc / sg;
        #pragma unroll
        for (int j = 0; j < 8; j++)
            out8[j] = 0.5f * sf[j] + 0.5f * (wi * ac[j] + ws * bc[j]);
        op = u1 + (size_t)r * DIM + 8 * l8;
    } else {
        float a_self = att_scalar(d1, b1v[4], w2v[4], b2v[4], 1.0f);
        float a_cust = att_scalar(d2, b1v[5], w2v[5], b2v[5], 1.0f);
        float sg = a_self + a_cust;
        float wi = a_self / sg, ws = a_cust / sg;
        #pragma unroll
        for (int j = 0; j < 8; j++)
            out8[j] = wi * sf[j] + ws * ac[j];
        op = i1 + (size_t)r * DIM + 8 * l8;
    }
    *(float4*)op = make_float4(out8[0], out8[1], out8[2], out8[3]);
    *(float4*)(op + 4) = make_float4(out8[4], out8[5], out8[6], out8[7]);
}

__global__ void layer2_kernel(const float* __restrict__ u1, const float* __restrict__ i1,
                              const int* __restrict__ ptr, const uint2* __restrict__ rec,
                              const float* __restrict__ W1, const float* __restrict__ b1v,
                              const float* __restrict__ w2v, const float* __restrict__ b2v,
                              const int* __restrict__ uidx, const int* __restrict__ iidx,
                              float* __restrict__ u2s, float* __restrict__ i2s, int U, int B) {
    int wid = blockIdx.x * (blockDim.x >> 6) + (threadIdx.x >> 6);
    int lane = threadIdx.x & 63;
    if (wid >= 2 * B) return;
    int g = lane >> 3, l8 = lane & 7;
    bool is_user = wid < B;
    int b = is_user ? wid : wid - B;
    int r = is_user ? uidx[b] : iidx[b];

    float acc_a[8] = {0, 0, 0, 0, 0, 0, 0, 0};
    float acc_b[8] = {0, 0, 0, 0, 0, 0, 0, 0};
    float s_a = 0.f, s_b = 0.f;

    if (is_user) {
        int e0 = ptr[U + r], e1 = ptr[U + r + 1];
        for (int e = e0 + g; e < e1; e += 8) {
            uint2 q = rec[e];
            float a = __uint_as_float(q.y & 0xffff0000u);  // bf16 t2
            s_a += a;
            const float4* rp = (const float4*)(i1 + (size_t)q.x * DIM);
            float4 v0 = rp[2 * l8], v1 = rp[2 * l8 + 1];
            acc_a[0] = fmaf(a, v0.x, acc_a[0]); acc_a[1] = fmaf(a, v0.y, acc_a[1]);
            acc_a[2] = fmaf(a, v0.z, acc_a[2]); acc_a[3] = fmaf(a, v0.w, acc_a[3]);
            acc_a[4] = fmaf(a, v1.x, acc_a[4]); acc_a[5] = fmaf(a, v1.y, acc_a[5]);
            acc_a[6] = fmaf(a, v1.z, acc_a[6]); acc_a[7] = fmaf(a, v1.w, acc_a[7]);
        }
        e0 = ptr[r]; e1 = ptr[r + 1];
        for (int e = e0 + g; e < e1; e += 8) {
            uint2 q = rec[e];
            float a = __uint_as_float(q.y & 0xffff0000u);
            s_b += a;
            const float4* rp = (const float4*)(u1 + (size_t)q.x * DIM);
            float4 v0 = rp[2 * l8], v1 = rp[2 * l8 + 1];
            acc_b[0] = fmaf(a, v0.x, acc_b[0]); acc_b[1] = fmaf(a, v0.y, acc_b[1]);
            acc_b[2] = fmaf(a, v0.z, acc_b[2]); acc_b[3] = fmaf(a, v0.w, acc_b[3]);
            acc_b[4] = fmaf(a, v1.x, acc_b[4]); acc_b[5] = fmaf(a, v1.y, acc_b[5]);
            acc_b[6] = fmaf(a, v1.z, acc_b[6]); acc_b[7] = fmaf(a, v1.w, acc_b[7]);
        }
    } else {
        int e0 = ptr[2 * U + r], e1 = ptr[2 * U + r + 1];
        for (int e = e0 + g; e < e1; e += 8) {
            uint2 q = rec[e];
            float a = __uint_as_float(q.y & 0xffff0000u);
            s_a += a;
            const float4* rp = (const float4*)(u1 + (size_t)q.x * DIM);
            float4 v0 = rp[2 * l8], v1 = rp[2 * l8 + 1];
            acc_a[0] = fmaf(a, v0.x, acc_a[0]); acc_a[1] = fmaf(a, v0.y, acc_a[1]);
            acc_a[2] = fmaf(a, v0.z, acc_a[2]); acc_a[3] = fmaf(a, v0.w, acc_a[3]);
            acc_a[4] = fmaf(a, v1.x, acc_a[4]); acc_a[5] = fmaf(a, v1.y, acc_a[5]);
            acc_a[6] = fmaf(a, v1.z, acc_a[6]); acc_a[7] = fmaf(a, v1.w, acc_a[7]);
        }
    }

    #pragma unroll
    for (int off = 8; off < 64; off <<= 1) {
        s_a += __shfl_xor(s_a, off, 64);
        #pragma unroll
        for (int j = 0; j < 8; j++) acc_a[j] += __shfl_xor(acc_a[j], off, 64);
    }
    if (is_user) {
        #pragma unroll
        for (int off = 8; off < 64; off <<= 1) {
            s_b += __shfl_xor(s_b, off, 64);
            #pragma unroll
            for (int j = 0; j < 8; j++) acc_b[j] += __shfl_xor(acc_b[j], off, 64);
        }
    }
    float ka = 1.0f / (s_a + 1e-12f);
    float kb = 1.0f / (s_b + 1e-12f);

    if (g == 0) {
        #pragma unroll
        for (int j = 0; j < 8; j++) { acc_a[j] *= ka; acc_b[j] *= kb; }
        const float* selfp = (is_user ? u1 : i1) + (size_t)r * DIM + 8 * l8;
        float4 s0 = *(const float4*)selfp;
        float4 s1 = *(const float4*)(selfp + 4);
        float sf[8] = {s0.x, s0.y, s0.z, s0.w, s1.x, s1.y, s1.z, s1.w};
        int k = is_user ? 2 : 6;
        const float* Wa = W1 + k * 2 * DIM;
        const float* Wb = Wa + 2 * DIM;
        float d1 = 0.f, d2 = 0.f;
        #pragma unroll
        for (int j = 0; j < 8; j++) {
            float wa0 = Wa[8 * l8 + j], wa1 = Wa[DIM + 8 * l8 + j];
            float wb0 = Wb[8 * l8 + j], wb1 = Wb[DIM + 8 * l8 + j];
            if (is_user) {
                d1 += sf[j] * wa0 + acc_a[j] * wa1;
                d2 += sf[j] * wb0 + acc_b[j] * wb1;
            } else {
                d1 += sf[j] * (wa0 + wa1);
                d2 += sf[j] * wb0 + acc_a[j] * wb1;
            }
        }
        d1 = dot8_lanes(d1);
        d2 = dot8_lanes(d2);

        float out8[8];
        float* op;
        if (is_user) {
            float a_int = att_scalar(d1, b1v[2], w2v[2], b2v[2], 0.7f);
            float a_soc = att_scalar(d2, b1v[3], w2v[3], b2v[3], 0.3f);
            float sg = a_int + a_soc;
            float wi = a_int / sg, ws = a_soc / sg;
            #pragma unroll
            for (int j = 0; j < 8; j++)
                out8[j] = 0.5f * sf[j] + 0.5f * (wi * acc_a[j] + ws * acc_b[j]);
            op = u2s + (size_t)b * DIM + 8 * l8;
        } else {
            float a_self = att_scalar(d1, b1v[6], w2v[6], b2v[6], 1.0f);
            float a_cust = att_scalar(d2, b1v[7], w2v[7], b2v[7], 1.0f);
            float sg = a_self + a_cust;
            float wi = a_self / sg, ws = a_cust / sg;
            #pragma unroll
            for (int j = 0; j < 8; j++)
                out8[j] = wi * sf[j] + ws * acc_a[j];
            op = i2s + (size_t)b * DIM + 8 * l8;
        }
        *(float4*)op = make_float4(out8[0], out8[1], out8[2], out8[3]);
        *(float4*)(op + 4) = make_float4(out8[4], out8[5], out8[6], out8[7]);
    }
}

// ---------------- final: sigmoid(dot over [u0|u1|u2] . [i0|i1|i2]) ----------------

__global__ void final_kernel(const float* __restrict__ u0, const float* __restrict__ u1,
                             const float* __restrict__ u2s,
                             const float* __restrict__ i0, const float* __restrict__ i1,
                             const float* __restrict__ i2s,
                             const int* __restrict__ uidx, const int* __restrict__ iidx,
                             float* __restrict__ out, int n) {
    int b = blockIdx.x * (blockDim.x >> 6) + (threadIdx.x >> 6);
    int lane = threadIdx.x & 63;
    if (b >= n) return;
    size_t ur = (size_t)uidx[b] * DIM + lane;
    size_t ir = (size_t)iidx[b] * DIM + lane;
    size_t sr = (size_t)b * DIM + lane;
    float acc = u0[ur] * i0[ir] + u1[ur] * i1[ir] + u2s[sr] * i2s[sr];
    #pragma unroll
    for (int off = 32; off > 0; off >>= 1) acc += __shfl_xor(acc, off, 64);
    if (lane == 0) out[b] = 1.0f / (1.0f + expf(-acc));
}

// ---------------- launch ----------------

extern "C" void kernel_launch(void* const* d_in, const int* in_sizes, int n_in,
                              void* d_out, int out_size, void* d_ws, size_t ws_size,
                              hipStream_t stream) {
    const float* user_emb = (const float*)d_in[0];
    const float* item_emb = (const float*)d_in[1];
    const float* snii1 = (const float*)d_in[2];
    const float* snii2 = (const float*)d_in[3];
    const float* ciii1 = (const float*)d_in[4];
    const float* ciii2 = (const float*)d_in[5];
    const float* icii1 = (const float*)d_in[6];
    const float* icii2 = (const float*)d_in[7];
    const float* low_w = (const float*)d_in[8];
    const float* low_b = (const float*)d_in[9];
    const float* att1_W = (const float*)d_in[10];
    const float* att1_b = (const float*)d_in[11];
    const float* att2_w = (const float*)d_in[12];
    const float* att2_b = (const float*)d_in[13];
    const int* sn_row = (const int*)d_in[14];
    const int* sn_col = (const int*)d_in[15];
    const int* ci_row = (const int*)d_in[16];
    const int* ci_col = (const int*)d_in[17];
    const int* ic_row = (const int*)d_in[18];
    const int* ic_col = (const int*)d_in[19];
    const int* user_idx = (const int*)d_in[20];
    const int* item_idx = (const int*)d_in[21];
    float* out = (float*)d_out;

    const int Es  = in_sizes[2];
    const int Eui = in_sizes[4];
    const int Eiu = in_sizes[6];
    const int U = in_sizes[0] / DIM;
    const int I = in_sizes[1] / DIM;
    const int B = in_sizes[20];
    const int R = 2 * U + I;                // virtual rows: [0,U)=sn, [U,2U)=ci, [2U,2U+I)=ic
    const int E = Es + Eui + Eiu;
    const int K = (R + 63) >> 6;            // 64-row buckets; 3907 <= KMAX

    // ---- workspace carve (4-byte units, 16B-aligned) ----
    char* wsb = (char*)d_ws;
    size_t off = 0;
    auto alloc = [&](size_t n_units) {
        off = (off + 3) & ~(size_t)3;
        void* p = wsb + off * 4; off += n_units; return p;
    };

    int* cntBlk    = (int*)alloc((size_t)NBLK_P * K);
    int* baseBlk   = (int*)alloc((size_t)NBLK_P * K);
    int* total     = (int*)alloc(K);
    int* bucketPtr = (int*)alloc(K + 1);
    int* ptr       = (int*)alloc(R + 1);
    uint2* barr    = (uint2*)alloc((size_t)E * 2);
    uint2* rec     = (uint2*)alloc((size_t)E * 2);
    uchar_t* ub8 = (uchar_t*)alloc((size_t)U * DIM / 4);
    uchar_t* ib8 = (uchar_t*)alloc((size_t)I * DIM / 4);
    float* u1  = (float*)alloc((size_t)U * DIM);
    float* i1  = (float*)alloc((size_t)I * DIM);
    float* u2s = (float*)alloc((size_t)B * DIM);
    float* i2s = (float*)alloc((size_t)B * DIM);
    (void)ws_size;

    size_t n8u = (size_t)U * DIM / 8, n8t = (size_t)(U + I) * DIM / 8;

    // ---- CSR build (5 dispatches): count | base | scan | place | finalize(+cvt) ----
    count_kernel<<<NBLK_P, NTHR, 0, stream>>>(sn_row, ci_row, ic_row, cntBlk,
                                              Es, Eui, Eiu, U, K);
    base_kernel<<<(K + 255) / 256, 256, 0, stream>>>(cntBlk, baseBlk, total, K);
    scan_kernel<<<1, NTHR, 0, stream>>>(total, bucketPtr, K, E);
    place_kernel<<<NBLK_P, NTHR, 0, stream>>>(sn_row, sn_col, ci_row, ci_col, ic_row, ic_col,
                                              snii1, snii2, ciii1, ciii2, icii1, icii2,
                                              low_w, low_b, bucketPtr, baseBlk, barr,
                                              Es, Eui, Eiu, U, K);
    finalize_kernel<<<K, 256, 0, stream>>>(user_emb, item_emb, ub8, ib8, n8u, n8t,
                                           barr, bucketPtr, ptr, rec, R, K, E);

    // ---- layer 1: one row per 8-lane group, 32 rows per 256-thr block ----
    layer1_kernel<<<(U + I + 31) / 32, 256, 0, stream>>>(ub8, ib8, user_emb, item_emb,
        ptr, rec, att1_W, att1_b, att2_w, att2_b, u1, i1, U, I);

    // ---- layer 2 (merged, sampled rows only) ----
    layer2_kernel<<<(2 * B + 3) / 4, 256, 0, stream>>>(u1, i1, ptr, rec,
        att1_W, att1_b, att2_w, att2_b, user_idx, item_idx, u2s, i2s, U, B);

    // ---- final gather-dot-sigmoid ----
    final_kernel<<<(B + 3) / 4, 256, 0, stream>>>(user_emb, u1, u2s, item_emb, i1, i2s,
                                                  user_idx, item_idx, out, B);
}

// Round 10
// 305.575 us; speedup vs baseline: 1.3759x; 1.2319x over previous
//
#include <hip/hip_runtime.h>
#include <math.h>

#define DIM 64
#define NBLK_P 512       // count/place blocks; 2/CU. R9 lesson: never fewer blocks than CUs.
#define NTHR 1024
#define CBSZ 1024        // rows per coarse bucket (R10): (block,bucket) run ~22 rec = 178B
                         // -> ~1.4x write amp (vs 3.3x at 64-row buckets, R3 PMC) AND full
                         // occupancy (vs 8.9% at NBLK=64, R9 PMC).
#define CBMAX 256        // CB = ceil(R/1024) = 245 <= 256

// PMC-verified lessons: R5/R8 global atomics & scattered 8B stores = line-granular HBM
// round-trips (atomics stay in LDS); R6 1024-thr layer blocks -> degree-variance tail.

typedef unsigned short ushort_t;
typedef unsigned int uint_t;
typedef unsigned char uchar_t;
typedef float v2f __attribute__((ext_vector_type(2)));

__device__ __forceinline__ ushort_t f2bf(float f) {
    uint_t u = __float_as_uint(f);
    return (ushort_t)((u + 0x7fffu + ((u >> 16) & 1u)) >> 16);
}

// ---------------- pass 1: fp8 tables + per-(block, coarse-bucket) counts ----------------

__global__ void count_cvt_kernel(const float* __restrict__ u0, const float* __restrict__ i0,
                                 uchar_t* __restrict__ ub, uchar_t* __restrict__ ib,
                                 size_t n8u, size_t n8t,
                                 const int* __restrict__ sn_row, const int* __restrict__ ci_row,
                                 const int* __restrict__ ic_row, int* __restrict__ cnt,
                                 int Es, int Eui, int Eiu, int U, int CB) {
    __shared__ int h[CBMAX];
    int b = blockIdx.x, tid = threadIdx.x;
    size_t gtid = (size_t)b * NTHR + tid;
    const size_t GT = (size_t)NBLK_P * NTHR;

    // fp8 conversion (emb ~N(0,0.01^2) x256 in e4m3 normal range; verified absmax 0.0)
    for (size_t i = gtid; i < n8t; i += GT) {
        const float4* src; uchar_t* dst; size_t di;
        if (i < n8u) { src = (const float4*)u0; dst = ub; di = i; }
        else         { src = (const float4*)i0; dst = ib; di = i - n8u; }
        float4 a = src[2 * di], c = src[2 * di + 1];
        int lo = 0, hi = 0;
        lo = __builtin_amdgcn_cvt_pk_fp8_f32(a.x * 256.0f, a.y * 256.0f, lo, false);
        lo = __builtin_amdgcn_cvt_pk_fp8_f32(a.z * 256.0f, a.w * 256.0f, lo, true);
        hi = __builtin_amdgcn_cvt_pk_fp8_f32(c.x * 256.0f, c.y * 256.0f, hi, false);
        hi = __builtin_amdgcn_cvt_pk_fp8_f32(c.z * 256.0f, c.w * 256.0f, hi, true);
        ((uint2*)dst)[di] = make_uint2((uint_t)lo, (uint_t)hi);
    }

    int E = Es + Eui + Eiu;
    int per = (E + NBLK_P - 1) / NBLK_P;
    int e0 = b * per, e1 = min(e0 + per, E);
    if (tid < CBMAX) h[tid] = 0;
    __syncthreads();
    for (int e = e0 + tid; e < e1; e += NTHR) {
        int r;
        if (e < Es) r = sn_row[e];
        else if (e < Es + Eui) r = U + ci_row[e - Es];
        else r = 2 * U + ic_row[e - Es - Eui];
        atomicAdd(&h[r >> 10], 1);
    }
    __syncthreads();
    if (tid < CB) cnt[(size_t)b * CB + tid] = h[tid];
}

// ---------------- pass 2: per-bucket exclusive scan over 512 blocks (CB-parallel) ------------

__global__ void blkscan_kernel(const int* __restrict__ cnt, int* __restrict__ blkoff,
                               int* __restrict__ total, int CB) {
    int c = blockIdx.x;
    int b = threadIdx.x;                  // NBLK_P threads = 8 waves
    int v = cnt[(size_t)b * CB + c];
    int lane = b & 63, wid = b >> 6;
    int inc = v;
    #pragma unroll
    for (int off = 1; off < 64; off <<= 1) {
        int x = __shfl_up(inc, off, 64);
        if (lane >= off) inc += x;
    }
    __shared__ int ws[NBLK_P / 64];
    if (lane == 63) ws[wid] = inc;
    __syncthreads();
    int woff = 0;
    for (int j = 0; j < wid; j++) woff += ws[j];
    blkoff[(size_t)b * CB + c] = inc - v + woff;
    if (b == NBLK_P - 1) total[c] = inc + woff;
}

// ---------------- pass 3: exclusive scan of CB bucket totals (1 block) ----------------------

__global__ void cstart_kernel(const int* __restrict__ total, int* __restrict__ cstart, int CB) {
    int t = threadIdx.x;                  // 256 threads = 4 waves
    int v = (t < CB) ? total[t] : 0;
    int lane = t & 63, wid = t >> 6;
    int inc = v;
    #pragma unroll
    for (int off = 1; off < 64; off <<= 1) {
        int x = __shfl_up(inc, off, 64);
        if (lane >= off) inc += x;
    }
    __shared__ int ws[4];
    if (lane == 63) ws[wid] = inc;
    __syncthreads();
    int woff = 0;
    for (int j = 0; j < wid; j++) woff += ws[j];
    if (t < CB) cstart[t] = inc - v + woff;
    if (t == CB - 1) cstart[CB] = inc + woff;     // = E
}

// ---------------- pass 4: place 8B records {rin10<<22|col, bf16(t2)<<16|bf16(t1)} ------------
// t = exp(exp(sigmoid(raw*w+b))) in (2.72,15.2): softmax w/o max-sub is safe; LDS atomics only.
// cur[c] preloaded (coalesced, 245 ints): zero random gathers in per-edge chain; runs of
// ~22 records per (block,bucket) keep barr writes near-full-line. col < 2^22 (U=1e5).

__global__ void place_kernel(const int* __restrict__ sn_row, const int* __restrict__ sn_col,
                             const int* __restrict__ ci_row, const int* __restrict__ ci_col,
                             const int* __restrict__ ic_row, const int* __restrict__ ic_col,
                             const float* __restrict__ snii1, const float* __restrict__ snii2,
                             const float* __restrict__ ciii1, const float* __restrict__ ciii2,
                             const float* __restrict__ icii1, const float* __restrict__ icii2,
                             const float* __restrict__ lw, const float* __restrict__ lb,
                             const int* __restrict__ cstart, const int* __restrict__ blkoff,
                             uint2* __restrict__ barr,
                             int Es, int Eui, int Eiu, int U, int CB) {
    __shared__ int cur[CBMAX];
    int E = Es + Eui + Eiu;
    int per = (E + NBLK_P - 1) / NBLK_P;
    int b = blockIdx.x;
    int e0 = b * per, e1 = min(e0 + per, E);
    if (threadIdx.x < CB)
        cur[threadIdx.x] = cstart[threadIdx.x] + blkoff[(size_t)b * CB + threadIdx.x];
    __syncthreads();
    for (int e = e0 + (int)threadIdx.x; e < e1; e += NTHR) {
        int r, c, j1, j2;
        float r1, r2;
        if (e < Es) {
            r = sn_row[e]; c = sn_col[e]; r1 = snii1[e]; r2 = snii2[e]; j1 = 0; j2 = 1;
        } else if (e < Es + Eui) {
            int t = e - Es;
            r = U + ci_row[t]; c = ci_col[t]; r1 = ciii1[t]; r2 = ciii2[t]; j1 = 2; j2 = 3;
        } else {
            int t = e - Es - Eui;
            r = 2 * U + ic_row[t]; c = ic_col[t]; r1 = icii1[t]; r2 = icii2[t]; j1 = 4; j2 = 5;
        }
        float t1 = expf(expf(1.0f / (1.0f + expf(-(r1 * lw[j1] + lb[j1])))));
        float t2 = expf(expf(1.0f / (1.0f + expf(-(r2 * lw[j2] + lb[j2])))));
        uint_t packed = (uint_t)f2bf(t1) | ((uint_t)f2bf(t2) << 16);
        int cb = r >> 10;
        int pos = atomicAdd(&cur[cb], 1);
        barr[pos] = make_uint2(((uint_t)(r & 1023) << 22) | (uint_t)c, packed);
    }
}

// ---------------- pass 5: one block per coarse bucket: 1024-row histo + scan + scatter -------
// Single-writer dense rec region per block -> full-line writes; all atomics in LDS.

__global__ void finalize_kernel(const uint2* __restrict__ barr, const int* __restrict__ cstart,
                                int* __restrict__ ptr, uint2* __restrict__ rec,
                                int R, int CB) {
    __shared__ int hist[CBSZ];
    __shared__ int cur2[CBSZ];
    __shared__ int ws[NTHR / 64];
    int c = blockIdx.x, tid = threadIdx.x;
    int s0 = cstart[c], s1 = cstart[c + 1];
    hist[tid] = 0;
    __syncthreads();
    for (int e = s0 + tid; e < s1; e += NTHR)
        atomicAdd(&hist[barr[e].x >> 22], 1);
    __syncthreads();
    int v = hist[tid];
    int lane = tid & 63, wid = tid >> 6;
    int inc = v;
    #pragma unroll
    for (int off = 1; off < 64; off <<= 1) {
        int x = __shfl_up(inc, off, 64);
        if (lane >= off) inc += x;
    }
    if (lane == 63) ws[wid] = inc;
    __syncthreads();
    int woff = 0;
    for (int j = 0; j < wid; j++) woff += ws[j];
    int p0 = s0 + inc - v + woff;                 // CSR start for row c*1024+tid
    int r = c * CBSZ + tid;
    if (r < R) ptr[r] = p0;
    cur2[tid] = p0;
    if (c == CB - 1 && tid == 0) ptr[R] = cstart[CB];
    __syncthreads();
    for (int e = s0 + tid; e < s1; e += NTHR) {
        uint2 q = barr[e];
        int rin = (int)(q.x >> 22);
        int pos = atomicAdd(&cur2[rin], 1);
        rec[pos] = make_uint2(q.x & 0x3FFFFFu, q.y);
    }
}

// ---------------- layer kernels ----------------

__device__ __forceinline__ float att_scalar(float dot, float b1, float w2, float b2, float addc) {
    float h = tanhf(dot + b1);
    float z = h * w2 + b2;
    float lr = z > 0.0f ? z : 0.2f * z;   // leaky_relu alpha=0.2
    return expf(lr) + addc;
}

// packed fp8 -> float2 FMA: 4 cvt + 4 packed FMAs per 8 dims (v_pk_fma_f32)
__device__ __forceinline__ void fp8_fma8v(v2f acc[4], uint2 v, float a) {
    v2f av = {a, a};
    acc[0] += av * __builtin_amdgcn_cvt_pk_f32_fp8((int)v.x, false);
    acc[1] += av * __builtin_amdgcn_cvt_pk_f32_fp8((int)v.x, true);
    acc[2] += av * __builtin_amdgcn_cvt_pk_f32_fp8((int)v.y, false);
    acc[3] += av * __builtin_amdgcn_cvt_pk_f32_fp8((int)v.y, true);
}

__device__ __forceinline__ float dot8_lanes(float d) {
    #pragma unroll
    for (int off = 1; off < 8; off <<= 1) d += __shfl_xor(d, off, 64);
    return d;
}

// BRANCH-FREE batched CSR walk (R14). 8 lanes load 8 different records (coalesced),
// prefetch next batch via clamped load + cndmask. Padded records are (0,0): cx=0 is a
// valid row-0 gather and a=0 makes the FMA a no-op -> no divergent branches, 8
// independent gathers clustered per batch.
__device__ __forceinline__ void agg_row8(const uint2* __restrict__ rec, const uchar_t* __restrict__ tab,
                                         int e0, int e1, int l8, int lanebase,
                                         v2f acc[4], float& s) {
    if (e0 >= e1) return;
    int last = e1 - 1;
    int idx0 = e0 + l8;
    uint2 t0 = rec[min(idx0, last)];
    uint2 q;
    q.x = (idx0 <= last) ? t0.x : 0u;
    q.y = (idx0 <= last) ? t0.y : 0u;
    for (int base = e0; base < e1; base += 8) {
        int nidx = base + 8 + l8;
        uint2 tn = rec[min(nidx, last)];          // unconditional clamped prefetch
        uint2 qn;
        qn.x = (nidx <= last) ? tn.x : 0u;
        qn.y = (nidx <= last) ? tn.y : 0u;
        s += __uint_as_float(q.y << 16);          // per-lane partial of bf16 t1 (0 if padded)
        #pragma unroll
        for (int j = 0; j < 8; j++) {
            uint_t cx = __shfl(q.x, lanebase + j, 64);
            uint_t wy = __shfl(q.y, lanebase + j, 64);
            float a = __uint_as_float(wy << 16);
            uint2 v = ((const uint2*)(tab + (size_t)cx * DIM))[l8];
            fp8_fma8v(acc, v, a);
        }
        q = qn;
    }
}

// one row per 8-lane group; 256-thr blocks (R6 lesson: 1024-thr blocks -> 41% occupancy).
__global__ void layer1_kernel(const uchar_t* __restrict__ ub8, const uchar_t* __restrict__ ib8,
                              const float* __restrict__ u0, const float* __restrict__ i0,
                              const int* __restrict__ ptr, const uint2* __restrict__ rec,
                              const float* __restrict__ W1, const float* __restrict__ b1v,
                              const float* __restrict__ w2v, const float* __restrict__ b2v,
                              float* __restrict__ u1, float* __restrict__ i1, int U, int I) {
    int gid = blockIdx.x * (blockDim.x >> 3) + (threadIdx.x >> 3);
    int lane = threadIdx.x & 63;
    int l8 = lane & 7;
    int lanebase = lane & 56;
    if (gid >= U + I) return;
    bool is_user = gid < U;
    int r = is_user ? gid : gid - U;

    v2f A[4]  = {{0.f, 0.f}, {0.f, 0.f}, {0.f, 0.f}, {0.f, 0.f}};
    v2f Bv[4] = {{0.f, 0.f}, {0.f, 0.f}, {0.f, 0.f}, {0.f, 0.f}};
    float s_a = 0.f, s_b = 0.f;

    if (is_user) {
        agg_row8(rec, ib8, ptr[U + r], ptr[U + r + 1], l8, lanebase, A, s_a);   // u_from_i (ci)
        agg_row8(rec, ub8, ptr[r], ptr[r + 1], l8, lanebase, Bv, s_b);          // u_from_u (sn)
    } else {
        agg_row8(rec, ub8, ptr[2 * U + r], ptr[2 * U + r + 1], l8, lanebase, A, s_a);  // i_from_u (ic)
    }
    s_a = dot8_lanes(s_a);
    s_b = dot8_lanes(s_b);

    float ka = (1.0f / (s_a + 1e-12f)) * 0.00390625f;   // softmax denom * fp8 scale
    float kb = (1.0f / (s_b + 1e-12f)) * 0.00390625f;
    float ac[8], bc[8];
    #pragma unroll
    for (int j = 0; j < 4; j++) {
        ac[2 * j] = A[j][0] * ka;  ac[2 * j + 1] = A[j][1] * ka;
        bc[2 * j] = Bv[j][0] * kb; bc[2 * j + 1] = Bv[j][1] * kb;
    }

    const float* selfp = (is_user ? u0 : i0) + (size_t)r * DIM + 8 * l8;
    float4 s0 = *(const float4*)selfp;
    float4 s1 = *(const float4*)(selfp + 4);
    float sf[8] = {s0.x, s0.y, s0.z, s0.w, s1.x, s1.y, s1.z, s1.w};
    int k = is_user ? 0 : 4;
    const float* Wa = W1 + k * 2 * DIM;
    const float* Wb = Wa + 2 * DIM;
    float d1 = 0.f, d2 = 0.f;
    #pragma unroll
    for (int j = 0; j < 8; j++) {
        float wa0 = Wa[8 * l8 + j], wa1 = Wa[DIM + 8 * l8 + j];
        float wb0 = Wb[8 * l8 + j], wb1 = Wb[DIM + 8 * l8 + j];
        if (is_user) {
            d1 += sf[j] * wa0 + ac[j] * wa1;
            d2 += sf[j] * wb0 + bc[j] * wb1;
        } else {
            d1 += sf[j] * (wa0 + wa1);                 // concat([it, it])
            d2 += sf[j] * wb0 + ac[j] * wb1;
        }
    }
    d1 = dot8_lanes(d1);
    d2 = dot8_lanes(d2);

    float out8[8];
    float* op;
    if (is_user) {
        float a_int = att_scalar(d1, b1v[0], w2v[0], b2v[0], 0.7f);
        float a_soc = att_scalar(d2, b1v[1], w2v[1], b2v[1], 0.3f);
        float sg = a_int + a_soc;
        float wi = a_int / sg, ws = a_soc / sg;
        #pragma unroll
        for (int j = 0; j < 8; j++)
            out8[j] = 0.5f * sf[j] + 0.5f * (wi * ac[j] + ws * bc[j]);
        op = u1 + (size_t)r * DIM + 8 * l8;
    } else {
        float a_self = att_scalar(d1, b1v[4], w2v[4], b2v[4], 1.0f);
        float a_cust = att_scalar(d2, b1v[5], w2v[5], b2v[5], 1.0f);
        float sg = a_self + a_cust;
        float wi = a_self / sg, ws = a_cust / sg;
        #pragma unroll
        for (int j = 0; j < 8; j++)
            out8[j] = wi * sf[j] + ws * ac[j];
        op = i1 + (size_t)r * DIM + 8 * l8;
    }
    *(float4*)op = make_float4(out8[0], out8[1], out8[2], out8[3]);
    *(float4*)(op + 4) = make_float4(out8[4], out8[5], out8[6], out8[7]);
}

__global__ void layer2_kernel(const float* __restrict__ u1, const float* __restrict__ i1,
                              const int* __restrict__ ptr, const uint2* __restrict__ rec,
                              const float* __restrict__ W1, const float* __restrict__ b1v,
                              const float* __restrict__ w2v, const float* __restrict__ b2v,
                              const int* __restrict__ uidx, const int* __restrict__ iidx,
                              float* __restrict__ u2s, float* __restrict__ i2s, int U, int B) {
    int wid = blockIdx.x * (blockDim.x >> 6) + (threadIdx.x >> 6);
    int lane = threadIdx.x & 63;
    if (wid >= 2 * B) return;
    int g = lane >> 3, l8 = lane & 7;
    bool is_user = wid < B;
    int b = is_user ? wid : wid - B;
    int r = is_user ? uidx[b] : iidx[b];

    float acc_a[8] = {0, 0, 0, 0, 0, 0, 0, 0};
    float acc_b[8] = {0, 0, 0, 0, 0, 0, 0, 0};
    float s_a = 0.f, s_b = 0.f;

    if (is_user) {
        int e0 = ptr[U + r], e1 = ptr[U + r + 1];
        for (int e = e0 + g; e < e1; e += 8) {
            uint2 q = rec[e];
            float a = __uint_as_float(q.y & 0xffff0000u);  // bf16 t2
            s_a += a;
            const float4* rp = (const float4*)(i1 + (size_t)q.x * DIM);
            float4 v0 = rp[2 * l8], v1 = rp[2 * l8 + 1];
            acc_a[0] = fmaf(a, v0.x, acc_a[0]); acc_a[1] = fmaf(a, v0.y, acc_a[1]);
            acc_a[2] = fmaf(a, v0.z, acc_a[2]); acc_a[3] = fmaf(a, v0.w, acc_a[3]);
            acc_a[4] = fmaf(a, v1.x, acc_a[4]); acc_a[5] = fmaf(a, v1.y, acc_a[5]);
            acc_a[6] = fmaf(a, v1.z, acc_a[6]); acc_a[7] = fmaf(a, v1.w, acc_a[7]);
        }
        e0 = ptr[r]; e1 = ptr[r + 1];
        for (int e = e0 + g; e < e1; e += 8) {
            uint2 q = rec[e];
            float a = __uint_as_float(q.y & 0xffff0000u);
            s_b += a;
            const float4* rp = (const float4*)(u1 + (size_t)q.x * DIM);
            float4 v0 = rp[2 * l8], v1 = rp[2 * l8 + 1];
            acc_b[0] = fmaf(a, v0.x, acc_b[0]); acc_b[1] = fmaf(a, v0.y, acc_b[1]);
            acc_b[2] = fmaf(a, v0.z, acc_b[2]); acc_b[3] = fmaf(a, v0.w, acc_b[3]);
            acc_b[4] = fmaf(a, v1.x, acc_b[4]); acc_b[5] = fmaf(a, v1.y, acc_b[5]);
            acc_b[6] = fmaf(a, v1.z, acc_b[6]); acc_b[7] = fmaf(a, v1.w, acc_b[7]);
        }
    } else {
        int e0 = ptr[2 * U + r], e1 = ptr[2 * U + r + 1];
        for (int e = e0 + g; e < e1; e += 8) {
            uint2 q = rec[e];
            float a = __uint_as_float(q.y & 0xffff0000u);
            s_a += a;
            const float4* rp = (const float4*)(u1 + (size_t)q.x * DIM);
            float4 v0 = rp[2 * l8], v1 = rp[2 * l8 + 1];
            acc_a[0] = fmaf(a, v0.x, acc_a[0]); acc_a[1] = fmaf(a, v0.y, acc_a[1]);
            acc_a[2] = fmaf(a, v0.z, acc_a[2]); acc_a[3] = fmaf(a, v0.w, acc_a[3]);
            acc_a[4] = fmaf(a, v1.x, acc_a[4]); acc_a[5] = fmaf(a, v1.y, acc_a[5]);
            acc_a[6] = fmaf(a, v1.z, acc_a[6]); acc_a[7] = fmaf(a, v1.w, acc_a[7]);
        }
    }

    #pragma unroll
    for (int off = 8; off < 64; off <<= 1) {
        s_a += __shfl_xor(s_a, off, 64);
        #pragma unroll
        for (int j = 0; j < 8; j++) acc_a[j] += __shfl_xor(acc_a[j], off, 64);
    }
    if (is_user) {
        #pragma unroll
        for (int off = 8; off < 64; off <<= 1) {
            s_b += __shfl_xor(s_b, off, 64);
            #pragma unroll
            for (int j = 0; j < 8; j++) acc_b[j] += __shfl_xor(acc_b[j], off, 64);
        }
    }
    float ka = 1.0f / (s_a + 1e-12f);
    float kb = 1.0f / (s_b + 1e-12f);

    if (g == 0) {
        #pragma unroll
        for (int j = 0; j < 8; j++) { acc_a[j] *= ka; acc_b[j] *= kb; }
        const float* selfp = (is_user ? u1 : i1) + (size_t)r * DIM + 8 * l8;
        float4 s0 = *(const float4*)selfp;
        float4 s1 = *(const float4*)(selfp + 4);
        float sf[8] = {s0.x, s0.y, s0.z, s0.w, s1.x, s1.y, s1.z, s1.w};
        int k = is_user ? 2 : 6;
        const float* Wa = W1 + k * 2 * DIM;
        const float* Wb = Wa + 2 * DIM;
        float d1 = 0.f, d2 = 0.f;
        #pragma unroll
        for (int j = 0; j < 8; j++) {
            float wa0 = Wa[8 * l8 + j], wa1 = Wa[DIM + 8 * l8 + j];
            float wb0 = Wb[8 * l8 + j], wb1 = Wb[DIM + 8 * l8 + j];
            if (is_user) {
                d1 += sf[j] * wa0 + acc_a[j] * wa1;
                d2 += sf[j] * wb0 + acc_b[j] * wb1;
            } else {
                d1 += sf[j] * (wa0 + wa1);
                d2 += sf[j] * wb0 + acc_a[j] * wb1;
            }
        }
        d1 = dot8_lanes(d1);
        d2 = dot8_lanes(d2);

        float out8[8];
        float* op;
        if (is_user) {
            float a_int = att_scalar(d1, b1v[2], w2v[2], b2v[2], 0.7f);
            float a_soc = att_scalar(d2, b1v[3], w2v[3], b2v[3], 0.3f);
            float sg = a_int + a_soc;
            float wi = a_int / sg, ws = a_soc / sg;
            #pragma unroll
            for (int j = 0; j < 8; j++)
                out8[j] = 0.5f * sf[j] + 0.5f * (wi * acc_a[j] + ws * acc_b[j]);
            op = u2s + (size_t)b * DIM + 8 * l8;
        } else {
            float a_self = att_scalar(d1, b1v[6], w2v[6], b2v[6], 1.0f);
            float a_cust = att_scalar(d2, b1v[7], w2v[7], b2v[7], 1.0f);
            float sg = a_self + a_cust;
            float wi = a_self / sg, ws = a_cust / sg;
            #pragma unroll
            for (int j = 0; j < 8; j++)
                out8[j] = wi * sf[j] + ws * acc_a[j];
            op = i2s + (size_t)b * DIM + 8 * l8;
        }
        *(float4*)op = make_float4(out8[0], out8[1], out8[2], out8[3]);
        *(float4*)(op + 4) = make_float4(out8[4], out8[5], out8[6], out8[7]);
    }
}

// ---------------- final: sigmoid(dot over [u0|u1|u2] . [i0|i1|i2]) ----------------

__global__ void final_kernel(const float* __restrict__ u0, const float* __restrict__ u1,
                             const float* __restrict__ u2s,
                             const float* __restrict__ i0, const float* __restrict__ i1,
                             const float* __restrict__ i2s,
                             const int* __restrict__ uidx, const int* __restrict__ iidx,
                             float* __restrict__ out, int n) {
    int b = blockIdx.x * (blockDim.x >> 6) + (threadIdx.x >> 6);
    int lane = threadIdx.x & 63;
    if (b >= n) return;
    size_t ur = (size_t)uidx[b] * DIM + lane;
    size_t ir = (size_t)iidx[b] * DIM + lane;
    size_t sr = (size_t)b * DIM + lane;
    float acc = u0[ur] * i0[ir] + u1[ur] * i1[ir] + u2s[sr] * i2s[sr];
    #pragma unroll
    for (int off = 32; off > 0; off >>= 1) acc += __shfl_xor(acc, off, 64);
    if (lane == 0) out[b] = 1.0f / (1.0f + expf(-acc));
}

// ---------------- launch ----------------

extern "C" void kernel_launch(void* const* d_in, const int* in_sizes, int n_in,
                              void* d_out, int out_size, void* d_ws, size_t ws_size,
                              hipStream_t stream) {
    const float* user_emb = (const float*)d_in[0];
    const float* item_emb = (const float*)d_in[1];
    const float* snii1 = (const float*)d_in[2];
    const float* snii2 = (const float*)d_in[3];
    const float* ciii1 = (const float*)d_in[4];
    const float* ciii2 = (const float*)d_in[5];
    const float* icii1 = (const float*)d_in[6];
    const float* icii2 = (const float*)d_in[7];
    const float* low_w = (const float*)d_in[8];
    const float* low_b = (const float*)d_in[9];
    const float* att1_W = (const float*)d_in[10];
    const float* att1_b = (const float*)d_in[11];
    const float* att2_w = (const float*)d_in[12];
    const float* att2_b = (const float*)d_in[13];
    const int* sn_row = (const int*)d_in[14];
    const int* sn_col = (const int*)d_in[15];
    const int* ci_row = (const int*)d_in[16];
    const int* ci_col = (const int*)d_in[17];
    const int* ic_row = (const int*)d_in[18];
    const int* ic_col = (const int*)d_in[19];
    const int* user_idx = (const int*)d_in[20];
    const int* item_idx = (const int*)d_in[21];
    float* out = (float*)d_out;

    const int Es  = in_sizes[2];
    const int Eui = in_sizes[4];
    const int Eiu = in_sizes[6];
    const int U = in_sizes[0] / DIM;
    const int I = in_sizes[1] / DIM;
    const int B = in_sizes[20];
    const int R = 2 * U + I;                // virtual rows: [0,U)=sn, [U,2U)=ci, [2U,2U+I)=ic
    const int E = Es + Eui + Eiu;
    const int CB = (R + CBSZ - 1) / CBSZ;   // 245 coarse buckets <= CBMAX

    // ---- workspace carve (4-byte units, 16B-aligned) ----
    char* wsb = (char*)d_ws;
    size_t off = 0;
    auto alloc = [&](size_t n_units) {
        off = (off + 3) & ~(size_t)3;
        void* p = wsb + off * 4; off += n_units; return p;
    };

    int* cnt    = (int*)alloc((size_t)NBLK_P * CB);
    int* blkoff = (int*)alloc((size_t)NBLK_P * CB);
    int* total  = (int*)alloc(CB);
    int* cstart = (int*)alloc(CB + 1);
    int* ptr    = (int*)alloc(R + 1);
    uint2* barr = (uint2*)alloc((size_t)E * 2);
    uint2* rec  = (uint2*)alloc((size_t)E * 2);
    uchar_t* ub8 = (uchar_t*)alloc((size_t)U * DIM / 4);
    uchar_t* ib8 = (uchar_t*)alloc((size_t)I * DIM / 4);
    float* u1  = (float*)alloc((size_t)U * DIM);
    float* i1  = (float*)alloc((size_t)I * DIM);
    float* u2s = (float*)alloc((size_t)B * DIM);
    float* i2s = (float*)alloc((size_t)B * DIM);
    (void)ws_size;

    size_t n8u = (size_t)U * DIM / 8, n8t = (size_t)(U + I) * DIM / 8;

    // ---- CSR build (5 dispatches): cvt+count | blkscan | cstart | place | finalize ----
    count_cvt_kernel<<<NBLK_P, NTHR, 0, stream>>>(user_emb, item_emb, ub8, ib8, n8u, n8t,
                                                  sn_row, ci_row, ic_row, cnt,
                                                  Es, Eui, Eiu, U, CB);
    blkscan_kernel<<<CB, NBLK_P, 0, stream>>>(cnt, blkoff, total, CB);
    cstart_kernel<<<1, 256, 0, stream>>>(total, cstart, CB);
    place_kernel<<<NBLK_P, NTHR, 0, stream>>>(sn_row, sn_col, ci_row, ci_col, ic_row, ic_col,
                                              snii1, snii2, ciii1, ciii2, icii1, icii2,
                                              low_w, low_b, cstart, blkoff, barr,
                                              Es, Eui, Eiu, U, CB);
    finalize_kernel<<<CB, NTHR, 0, stream>>>(barr, cstart, ptr, rec, R, CB);

    // ---- layer 1: one row per 8-lane group, 32 rows per 256-thr block ----
    layer1_kernel<<<(U + I + 31) / 32, 256, 0, stream>>>(ub8, ib8, user_emb, item_emb,
        ptr, rec, att1_W, att1_b, att2_w, att2_b, u1, i1, U, I);

    // ---- layer 2 (merged, sampled rows only) ----
    layer2_kernel<<<(2 * B + 3) / 4, 256, 0, stream>>>(u1, i1, ptr, rec,
        att1_W, att1_b, att2_w, att2_b, user_idx, item_idx, u2s, i2s, U, B);

    // ---- final gather-dot-sigmoid ----
    final_kernel<<<(B + 3) / 4, 256, 0, stream>>>(user_emb, u1, u2s, item_emb, i1, i2s,
                                                  user_idx, item_idx, out, B);
}

// Round 11
// 290.550 us; speedup vs baseline: 1.4470x; 1.0517x over previous
//
#include <hip/hip_runtime.h>
#include <math.h>

#define DIM 64
#define NBLK_P 512       // count/place blocks; 2/CU. R9 lesson: never fewer blocks than CUs.
#define NTHR 1024
#define CBSZ 1024        // rows per coarse bucket (R10-verified): (block,bucket) run ~22 rec
                         // -> ~1.4x write amp AND full occupancy. 334->305us.
#define CBMAX 256        // CB = ceil(R/1024) = 245 <= 256

// PMC-verified lessons: R5/R8 global atomics & scattered 8B stores = line-granular HBM
// round-trips (atomics stay in LDS); R6 1024-thr layer blocks -> degree-variance tail;
// R9 grids < 256 blocks starve CUs.

typedef unsigned short ushort_t;
typedef unsigned int uint_t;
typedef unsigned char uchar_t;
typedef float v2f __attribute__((ext_vector_type(2)));

__device__ __forceinline__ ushort_t f2bf(float f) {
    uint_t u = __float_as_uint(f);
    return (ushort_t)((u + 0x7fffu + ((u >> 16) & 1u)) >> 16);
}

// ---------------- pass 1: fp8 tables + per-(block, coarse-bucket) counts (x4 vectorized) -----

__device__ __forceinline__ void count_list(const int* __restrict__ rows, int EL, int base,
                                           int* h, size_t gtid, size_t GT) {
    size_t nq = ((size_t)EL + 3) >> 2;
    for (size_t q = gtid; q < nq; q += GT) {
        int e = (int)(q << 2);
        if (e + 4 <= EL) {
            int4 r4 = *(const int4*)(rows + e);
            atomicAdd(&h[(base + r4.x) >> 10], 1);
            atomicAdd(&h[(base + r4.y) >> 10], 1);
            atomicAdd(&h[(base + r4.z) >> 10], 1);
            atomicAdd(&h[(base + r4.w) >> 10], 1);
        } else {
            for (int j = e; j < EL; j++) atomicAdd(&h[(base + rows[j]) >> 10], 1);
        }
    }
}

__global__ void count_cvt_kernel(const float* __restrict__ u0, const float* __restrict__ i0,
                                 uchar_t* __restrict__ ub, uchar_t* __restrict__ ib,
                                 size_t n8u, size_t n8t,
                                 const int* __restrict__ sn_row, const int* __restrict__ ci_row,
                                 const int* __restrict__ ic_row, int* __restrict__ cnt,
                                 int Es, int Eui, int Eiu, int U, int CB) {
    __shared__ int h[CBMAX];
    int b = blockIdx.x, tid = threadIdx.x;
    size_t gtid = (size_t)b * NTHR + tid;
    const size_t GT = (size_t)NBLK_P * NTHR;

    // fp8 conversion (emb ~N(0,0.01^2) x256 in e4m3 normal range; verified absmax 0.0)
    for (size_t i = gtid; i < n8t; i += GT) {
        const float4* src; uchar_t* dst; size_t di;
        if (i < n8u) { src = (const float4*)u0; dst = ub; di = i; }
        else         { src = (const float4*)i0; dst = ib; di = i - n8u; }
        float4 a = src[2 * di], c = src[2 * di + 1];
        int lo = 0, hi = 0;
        lo = __builtin_amdgcn_cvt_pk_fp8_f32(a.x * 256.0f, a.y * 256.0f, lo, false);
        lo = __builtin_amdgcn_cvt_pk_fp8_f32(a.z * 256.0f, a.w * 256.0f, lo, true);
        hi = __builtin_amdgcn_cvt_pk_fp8_f32(c.x * 256.0f, c.y * 256.0f, hi, false);
        hi = __builtin_amdgcn_cvt_pk_fp8_f32(c.z * 256.0f, c.w * 256.0f, hi, true);
        ((uint2*)dst)[di] = make_uint2((uint_t)lo, (uint_t)hi);
    }

    if (tid < CBMAX) h[tid] = 0;
    __syncthreads();
    count_list(sn_row, Es, 0, h, gtid, GT);
    count_list(ci_row, Eui, U, h, gtid, GT);
    count_list(ic_row, Eiu, 2 * U, h, gtid, GT);
    __syncthreads();
    if (tid < CB) cnt[(size_t)b * CB + tid] = h[tid];
}

// ---------------- pass 2: per-bucket exclusive scan over 512 blocks (CB-parallel) ------------

__global__ void blkscan_kernel(const int* __restrict__ cnt, int* __restrict__ blkoff,
                               int* __restrict__ total, int CB) {
    int c = blockIdx.x;
    int b = threadIdx.x;                  // NBLK_P threads = 8 waves
    int v = cnt[(size_t)b * CB + c];
    int lane = b & 63, wid = b >> 6;
    int inc = v;
    #pragma unroll
    for (int off = 1; off < 64; off <<= 1) {
        int x = __shfl_up(inc, off, 64);
        if (lane >= off) inc += x;
    }
    __shared__ int ws[NBLK_P / 64];
    if (lane == 63) ws[wid] = inc;
    __syncthreads();
    int woff = 0;
    for (int j = 0; j < wid; j++) woff += ws[j];
    blkoff[(size_t)b * CB + c] = inc - v + woff;
    if (b == NBLK_P - 1) total[c] = inc + woff;
}

// ---- inline CB-prefix (R11: replaces the cstart dispatch; ~2us redundant work/block) --------
// Requires blockDim >= 256; first 4 waves compute exclusive prefix of total[0..CB) into cs.

__device__ __forceinline__ void cb_prefix(const int* __restrict__ total, int CB,
                                          int* cs, int* wsx) {
    int t = threadIdx.x;
    int lane = t & 63, wv = t >> 6;
    int v = 0, inc = 0;
    if (t < 256) {
        v = (t < CB) ? total[t] : 0;
        inc = v;
        #pragma unroll
        for (int off = 1; off < 64; off <<= 1) {
            int x = __shfl_up(inc, off, 64);
            if (lane >= off) inc += x;
        }
        if (lane == 63) wsx[wv] = inc;
    }
    __syncthreads();
    if (t < 256) {
        int woff = 0;
        for (int j = 0; j < wv; j++) woff += wsx[j];
        if (t < CB) cs[t] = inc - v + woff;
        if (t == CB - 1) cs[CB] = inc + woff;     // = E
    }
    __syncthreads();
}

// ---------------- pass 3: place 8B records {rin10<<22|col, bf16(t2)<<16|bf16(t1)} ------------
// t = exp(exp(sigmoid(raw*w+b))) in (2.72,15.2): softmax w/o max-sub is safe; LDS atomics only.
// x4-vectorized edge reads with per-list hoisted weights (R8-proven quad mapping; must match
// count_list's mapping exactly for blkoff consistency). col < 2^22 (U=1e5).

__device__ __forceinline__ void place_edge(int v, int c, float r1, float r2,
                                           float w1, float b1, float w2, float b2,
                                           int* cur, uint2* __restrict__ barr) {
    float t1 = expf(expf(1.0f / (1.0f + expf(-(r1 * w1 + b1)))));
    float t2 = expf(expf(1.0f / (1.0f + expf(-(r2 * w2 + b2)))));
    uint_t packed = (uint_t)f2bf(t1) | ((uint_t)f2bf(t2) << 16);
    int pos = atomicAdd(&cur[v >> 10], 1);
    barr[pos] = make_uint2(((uint_t)(v & 1023) << 22) | (uint_t)c, packed);
}

__device__ __forceinline__ void place_list(const int* __restrict__ rows, const int* __restrict__ cols,
                                           const float* __restrict__ x1, const float* __restrict__ x2,
                                           int EL, int base, float w1, float b1, float w2, float b2,
                                           int* cur, uint2* __restrict__ barr,
                                           size_t gtid, size_t GT) {
    size_t nq = ((size_t)EL + 3) >> 2;
    for (size_t q = gtid; q < nq; q += GT) {
        int e = (int)(q << 2);
        if (e + 4 <= EL) {
            int4 r4 = *(const int4*)(rows + e);
            int4 c4 = *(const int4*)(cols + e);
            float4 a4 = *(const float4*)(x1 + e);
            float4 b4 = *(const float4*)(x2 + e);
            place_edge(base + r4.x, c4.x, a4.x, b4.x, w1, b1, w2, b2, cur, barr);
            place_edge(base + r4.y, c4.y, a4.y, b4.y, w1, b1, w2, b2, cur, barr);
            place_edge(base + r4.z, c4.z, a4.z, b4.z, w1, b1, w2, b2, cur, barr);
            place_edge(base + r4.w, c4.w, a4.w, b4.w, w1, b1, w2, b2, cur, barr);
        } else {
            for (int j = e; j < EL; j++)
                place_edge(base + rows[j], cols[j], x1[j], x2[j], w1, b1, w2, b2, cur, barr);
        }
    }
}

__global__ void place_kernel(const int* __restrict__ sn_row, const int* __restrict__ sn_col,
                             const int* __restrict__ ci_row, const int* __restrict__ ci_col,
                             const int* __restrict__ ic_row, const int* __restrict__ ic_col,
                             const float* __restrict__ snii1, const float* __restrict__ snii2,
                             const float* __restrict__ ciii1, const float* __restrict__ ciii2,
                             const float* __restrict__ icii1, const float* __restrict__ icii2,
                             const float* __restrict__ lw, const float* __restrict__ lb,
                             const int* __restrict__ total, const int* __restrict__ blkoff,
                             uint2* __restrict__ barr,
                             int Es, int Eui, int Eiu, int U, int CB) {
    __shared__ int cs[CBMAX + 1];
    __shared__ int wsx[4];
    __shared__ int cur[CBMAX];
    int b = blockIdx.x;
    cb_prefix(total, CB, cs, wsx);
    if (threadIdx.x < CB)
        cur[threadIdx.x] = cs[threadIdx.x] + blkoff[(size_t)b * CB + threadIdx.x];
    __syncthreads();
    size_t gtid = (size_t)b * NTHR + threadIdx.x;
    const size_t GT = (size_t)NBLK_P * NTHR;
    place_list(sn_row, sn_col, snii1, snii2, Es, 0,      lw[0], lb[0], lw[1], lb[1], cur, barr, gtid, GT);
    place_list(ci_row, ci_col, ciii1, ciii2, Eui, U,     lw[2], lb[2], lw[3], lb[3], cur, barr, gtid, GT);
    place_list(ic_row, ic_col, icii1, icii2, Eiu, 2 * U, lw[4], lb[4], lw[5], lb[5], cur, barr, gtid, GT);
}

// ---------------- pass 4: one block per coarse bucket: 1024-row histo + scan + scatter -------
// Single-writer dense rec region per block -> full-line writes; all atomics in LDS.

__global__ void finalize_kernel(const uint2* __restrict__ barr, const int* __restrict__ total,
                                int* __restrict__ ptr, uint2* __restrict__ rec,
                                int R, int CB) {
    __shared__ int cs[CBMAX + 1];
    __shared__ int wsx[4];
    __shared__ int hist[CBSZ];
    __shared__ int cur2[CBSZ];
    __shared__ int wss[NTHR / 64];
    int c = blockIdx.x, tid = threadIdx.x;
    cb_prefix(total, CB, cs, wsx);
    int s0 = cs[c], s1 = cs[c + 1];
    hist[tid] = 0;
    __syncthreads();
    for (int e = s0 + tid; e < s1; e += NTHR)
        atomicAdd(&hist[barr[e].x >> 22], 1);
    __syncthreads();
    int v = hist[tid];
    int lane = tid & 63, wid = tid >> 6;
    int inc = v;
    #pragma unroll
    for (int off = 1; off < 64; off <<= 1) {
        int x = __shfl_up(inc, off, 64);
        if (lane >= off) inc += x;
    }
    if (lane == 63) wss[wid] = inc;
    __syncthreads();
    int woff = 0;
    for (int j = 0; j < wid; j++) woff += wss[j];
    int p0 = s0 + inc - v + woff;                 // CSR start for row c*1024+tid
    int r = c * CBSZ + tid;
    if (r < R) ptr[r] = p0;
    cur2[tid] = p0;
    if (c == CB - 1 && tid == 0) ptr[R] = cs[CB];
    __syncthreads();
    for (int e = s0 + tid; e < s1; e += NTHR) {
        uint2 q = barr[e];
        int rin = (int)(q.x >> 22);
        int pos = atomicAdd(&cur2[rin], 1);
        rec[pos] = make_uint2(q.x & 0x3FFFFFu, q.y);
    }
}

// ---------------- layer kernels ----------------

__device__ __forceinline__ float att_scalar(float dot, float b1, float w2, float b2, float addc) {
    float h = tanhf(dot + b1);
    float z = h * w2 + b2;
    float lr = z > 0.0f ? z : 0.2f * z;   // leaky_relu alpha=0.2
    return expf(lr) + addc;
}

// packed fp8 -> float2 FMA: 4 cvt + 4 packed FMAs per 8 dims (v_pk_fma_f32)
__device__ __forceinline__ void fp8_fma8v(v2f acc[4], uint2 v, float a) {
    v2f av = {a, a};
    acc[0] += av * __builtin_amdgcn_cvt_pk_f32_fp8((int)v.x, false);
    acc[1] += av * __builtin_amdgcn_cvt_pk_f32_fp8((int)v.x, true);
    acc[2] += av * __builtin_amdgcn_cvt_pk_f32_fp8((int)v.y, false);
    acc[3] += av * __builtin_amdgcn_cvt_pk_f32_fp8((int)v.y, true);
}

__device__ __forceinline__ float dot8_lanes(float d) {
    #pragma unroll
    for (int off = 1; off < 8; off <<= 1) d += __shfl_xor(d, off, 64);
    return d;
}

// BRANCH-FREE batched CSR walk (R14). 8 lanes load 8 different records (coalesced),
// prefetch next batch via clamped load + cndmask. Padded records are (0,0): cx=0 is a
// valid row-0 gather and a=0 makes the FMA a no-op -> no divergent branches, 8
// independent gathers clustered per batch.
__device__ __forceinline__ void agg_row8(const uint2* __restrict__ rec, const uchar_t* __restrict__ tab,
                                         int e0, int e1, int l8, int lanebase,
                                         v2f acc[4], float& s) {
    if (e0 >= e1) return;
    int last = e1 - 1;
    int idx0 = e0 + l8;
    uint2 t0 = rec[min(idx0, last)];
    uint2 q;
    q.x = (idx0 <= last) ? t0.x : 0u;
    q.y = (idx0 <= last) ? t0.y : 0u;
    for (int base = e0; base < e1; base += 8) {
        int nidx = base + 8 + l8;
        uint2 tn = rec[min(nidx, last)];          // unconditional clamped prefetch
        uint2 qn;
        qn.x = (nidx <= last) ? tn.x : 0u;
        qn.y = (nidx <= last) ? tn.y : 0u;
        s += __uint_as_float(q.y << 16);          // per-lane partial of bf16 t1 (0 if padded)
        #pragma unroll
        for (int j = 0; j < 8; j++) {
            uint_t cx = __shfl(q.x, lanebase + j, 64);
            uint_t wy = __shfl(q.y, lanebase + j, 64);
            float a = __uint_as_float(wy << 16);
            uint2 v = ((const uint2*)(tab + (size_t)cx * DIM))[l8];
            fp8_fma8v(acc, v, a);
        }
        q = qn;
    }
}

// one row per 8-lane group; 256-thr blocks (R6 lesson: 1024-thr blocks -> 41% occupancy).
__global__ void layer1_kernel(const uchar_t* __restrict__ ub8, const uchar_t* __restrict__ ib8,
                              const float* __restrict__ u0, const float* __restrict__ i0,
                              const int* __restrict__ ptr, const uint2* __restrict__ rec,
                              const float* __restrict__ W1, const float* __restrict__ b1v,
                              const float* __restrict__ w2v, const float* __restrict__ b2v,
                              float* __restrict__ u1, float* __restrict__ i1, int U, int I) {
    int gid = blockIdx.x * (blockDim.x >> 3) + (threadIdx.x >> 3);
    int lane = threadIdx.x & 63;
    int l8 = lane & 7;
    int lanebase = lane & 56;
    if (gid >= U + I) return;
    bool is_user = gid < U;
    int r = is_user ? gid : gid - U;

    v2f A[4]  = {{0.f, 0.f}, {0.f, 0.f}, {0.f, 0.f}, {0.f, 0.f}};
    v2f Bv[4] = {{0.f, 0.f}, {0.f, 0.f}, {0.f, 0.f}, {0.f, 0.f}};
    float s_a = 0.f, s_b = 0.f;

    if (is_user) {
        agg_row8(rec, ib8, ptr[U + r], ptr[U + r + 1], l8, lanebase, A, s_a);   // u_from_i (ci)
        agg_row8(rec, ub8, ptr[r], ptr[r + 1], l8, lanebase, Bv, s_b);          // u_from_u (sn)
    } else {
        agg_row8(rec, ub8, ptr[2 * U + r], ptr[2 * U + r + 1], l8, lanebase, A, s_a);  // i_from_u (ic)
    }
    s_a = dot8_lanes(s_a);
    s_b = dot8_lanes(s_b);

    float ka = (1.0f / (s_a + 1e-12f)) * 0.00390625f;   // softmax denom * fp8 scale
    float kb = (1.0f / (s_b + 1e-12f)) * 0.00390625f;
    float ac[8], bc[8];
    #pragma unroll
    for (int j = 0; j < 4; j++) {
        ac[2 * j] = A[j][0] * ka;  ac[2 * j + 1] = A[j][1] * ka;
        bc[2 * j] = Bv[j][0] * kb; bc[2 * j + 1] = Bv[j][1] * kb;
    }

    const float* selfp = (is_user ? u0 : i0) + (size_t)r * DIM + 8 * l8;
    float4 s0 = *(const float4*)selfp;
    float4 s1 = *(const float4*)(selfp + 4);
    float sf[8] = {s0.x, s0.y, s0.z, s0.w, s1.x, s1.y, s1.z, s1.w};
    int k = is_user ? 0 : 4;
    const float* Wa = W1 + k * 2 * DIM;
    const float* Wb = Wa + 2 * DIM;
    float d1 = 0.f, d2 = 0.f;
    #pragma unroll
    for (int j = 0; j < 8; j++) {
        float wa0 = Wa[8 * l8 + j], wa1 = Wa[DIM + 8 * l8 + j];
        float wb0 = Wb[8 * l8 + j], wb1 = Wb[DIM + 8 * l8 + j];
        if (is_user) {
            d1 += sf[j] * wa0 + ac[j] * wa1;
            d2 += sf[j] * wb0 + bc[j] * wb1;
        } else {
            d1 += sf[j] * (wa0 + wa1);                 // concat([it, it])
            d2 += sf[j] * wb0 + ac[j] * wb1;
        }
    }
    d1 = dot8_lanes(d1);
    d2 = dot8_lanes(d2);

    float out8[8];
    float* op;
    if (is_user) {
        float a_int = att_scalar(d1, b1v[0], w2v[0], b2v[0], 0.7f);
        float a_soc = att_scalar(d2, b1v[1], w2v[1], b2v[1], 0.3f);
        float sg = a_int + a_soc;
        float wi = a_int / sg, ws = a_soc / sg;
        #pragma unroll
        for (int j = 0; j < 8; j++)
            out8[j] = 0.5f * sf[j] + 0.5f * (wi * ac[j] + ws * bc[j]);
        op = u1 + (size_t)r * DIM + 8 * l8;
    } else {
        float a_self = att_scalar(d1, b1v[4], w2v[4], b2v[4], 1.0f);
        float a_cust = att_scalar(d2, b1v[5], w2v[5], b2v[5], 1.0f);
        float sg = a_self + a_cust;
        float wi = a_self / sg, ws = a_cust / sg;
        #pragma unroll
        for (int j = 0; j < 8; j++)
            out8[j] = wi * sf[j] + ws * ac[j];
        op = i1 + (size_t)r * DIM + 8 * l8;
    }
    *(float4*)op = make_float4(out8[0], out8[1], out8[2], out8[3]);
    *(float4*)(op + 4) = make_float4(out8[4], out8[5], out8[6], out8[7]);
}

// ---------------- R11: fused layer2+final — one wave per sample; u2/i2 never hit global ------
// After the cross-group reduce, acc values are identical in all 64 lanes, so the epilogues
// run redundantly in all lanes (no g==0 masking); u2o/i2o per-lane dims feed the final dot.

__global__ void l2f_kernel(const float* __restrict__ u0, const float* __restrict__ i0,
                           const float* __restrict__ u1, const float* __restrict__ i1,
                           const int* __restrict__ ptr, const uint2* __restrict__ rec,
                           const float* __restrict__ W1, const float* __restrict__ b1v,
                           const float* __restrict__ w2v, const float* __restrict__ b2v,
                           const int* __restrict__ uidx, const int* __restrict__ iidx,
                           float* __restrict__ out, int U, int B) {
    int wid = blockIdx.x * (blockDim.x >> 6) + (threadIdx.x >> 6);
    int lane = threadIdx.x & 63;
    if (wid >= B) return;
    int g = lane >> 3, l8 = lane & 7;
    int ru = uidx[wid], ri = iidx[wid];

    // ---- user phase: u2 row of ru ----
    float aa[8] = {0, 0, 0, 0, 0, 0, 0, 0};
    float ab[8] = {0, 0, 0, 0, 0, 0, 0, 0};
    float s_a = 0.f, s_b = 0.f;
    int e0 = ptr[U + ru], e1 = ptr[U + ru + 1];
    for (int e = e0 + g; e < e1; e += 8) {
        uint2 q = rec[e];
        float a = __uint_as_float(q.y & 0xffff0000u);  // bf16 t2
        s_a += a;
        const float4* rp = (const float4*)(i1 + (size_t)q.x * DIM);
        float4 v0 = rp[2 * l8], v1 = rp[2 * l8 + 1];
        aa[0] = fmaf(a, v0.x, aa[0]); aa[1] = fmaf(a, v0.y, aa[1]);
        aa[2] = fmaf(a, v0.z, aa[2]); aa[3] = fmaf(a, v0.w, aa[3]);
        aa[4] = fmaf(a, v1.x, aa[4]); aa[5] = fmaf(a, v1.y, aa[5]);
        aa[6] = fmaf(a, v1.z, aa[6]); aa[7] = fmaf(a, v1.w, aa[7]);
    }
    e0 = ptr[ru]; e1 = ptr[ru + 1];
    for (int e = e0 + g; e < e1; e += 8) {
        uint2 q = rec[e];
        float a = __uint_as_float(q.y & 0xffff0000u);
        s_b += a;
        const float4* rp = (const float4*)(u1 + (size_t)q.x * DIM);
        float4 v0 = rp[2 * l8], v1 = rp[2 * l8 + 1];
        ab[0] = fmaf(a, v0.x, ab[0]); ab[1] = fmaf(a, v0.y, ab[1]);
        ab[2] = fmaf(a, v0.z, ab[2]); ab[3] = fmaf(a, v0.w, ab[3]);
        ab[4] = fmaf(a, v1.x, ab[4]); ab[5] = fmaf(a, v1.y, ab[5]);
        ab[6] = fmaf(a, v1.z, ab[6]); ab[7] = fmaf(a, v1.w, ab[7]);
    }
    #pragma unroll
    for (int off = 8; off < 64; off <<= 1) {
        s_a += __shfl_xor(s_a, off, 64);
        s_b += __shfl_xor(s_b, off, 64);
        #pragma unroll
        for (int j = 0; j < 8; j++) {
            aa[j] += __shfl_xor(aa[j], off, 64);
            ab[j] += __shfl_xor(ab[j], off, 64);
        }
    }
    float ka = 1.0f / (s_a + 1e-12f);
    float kb = 1.0f / (s_b + 1e-12f);
    #pragma unroll
    for (int j = 0; j < 8; j++) { aa[j] *= ka; ab[j] *= kb; }

    const float* sup = u1 + (size_t)ru * DIM + 8 * l8;
    float4 su0 = *(const float4*)sup;
    float4 su1 = *(const float4*)(sup + 4);
    float sfu[8] = {su0.x, su0.y, su0.z, su0.w, su1.x, su1.y, su1.z, su1.w};
    {
        const float* Wa = W1 + 2 * 2 * DIM;            // k=2
        const float* Wb = Wa + 2 * DIM;
        float d1 = 0.f, d2 = 0.f;
        #pragma unroll
        for (int j = 0; j < 8; j++) {
            d1 += sfu[j] * Wa[8 * l8 + j] + aa[j] * Wa[DIM + 8 * l8 + j];
            d2 += sfu[j] * Wb[8 * l8 + j] + ab[j] * Wb[DIM + 8 * l8 + j];
        }
        d1 = dot8_lanes(d1);
        d2 = dot8_lanes(d2);
        float a_int = att_scalar(d1, b1v[2], w2v[2], b2v[2], 0.7f);
        float a_soc = att_scalar(d2, b1v[3], w2v[3], b2v[3], 0.3f);
        float sg = a_int + a_soc;
        float wi = a_int / sg, ws = a_soc / sg;
        #pragma unroll
        for (int j = 0; j < 8; j++)
            aa[j] = 0.5f * sfu[j] + 0.5f * (wi * aa[j] + ws * ab[j]);   // aa := u2 dims
    }

    // ---- item phase: i2 row of ri ----
    float ac[8] = {0, 0, 0, 0, 0, 0, 0, 0};
    float s_c = 0.f;
    e0 = ptr[2 * U + ri]; e1 = ptr[2 * U + ri + 1];
    for (int e = e0 + g; e < e1; e += 8) {
        uint2 q = rec[e];
        float a = __uint_as_float(q.y & 0xffff0000u);
        s_c += a;
        const float4* rp = (const float4*)(u1 + (size_t)q.x * DIM);
        float4 v0 = rp[2 * l8], v1 = rp[2 * l8 + 1];
        ac[0] = fmaf(a, v0.x, ac[0]); ac[1] = fmaf(a, v0.y, ac[1]);
        ac[2] = fmaf(a, v0.z, ac[2]); ac[3] = fmaf(a, v0.w, ac[3]);
        ac[4] = fmaf(a, v1.x, ac[4]); ac[5] = fmaf(a, v1.y, ac[5]);
        ac[6] = fmaf(a, v1.z, ac[6]); ac[7] = fmaf(a, v1.w, ac[7]);
    }
    #pragma unroll
    for (int off = 8; off < 64; off <<= 1) {
        s_c += __shfl_xor(s_c, off, 64);
        #pragma unroll
        for (int j = 0; j < 8; j++) ac[j] += __shfl_xor(ac[j], off, 64);
    }
    float kc = 1.0f / (s_c + 1e-12f);
    #pragma unroll
    for (int j = 0; j < 8; j++) ac[j] *= kc;

    const float* sip = i1 + (size_t)ri * DIM + 8 * l8;
    float4 si0 = *(const float4*)sip;
    float4 si1 = *(const float4*)(sip + 4);
    float sfi[8] = {si0.x, si0.y, si0.z, si0.w, si1.x, si1.y, si1.z, si1.w};
    {
        const float* Wa = W1 + 6 * 2 * DIM;            // k=6
        const float* Wb = Wa + 2 * DIM;
        float d1 = 0.f, d2 = 0.f;
        #pragma unroll
        for (int j = 0; j < 8; j++) {
            d1 += sfi[j] * (Wa[8 * l8 + j] + Wa[DIM + 8 * l8 + j]);   // concat([it, it])
            d2 += sfi[j] * Wb[8 * l8 + j] + ac[j] * Wb[DIM + 8 * l8 + j];
        }
        d1 = dot8_lanes(d1);
        d2 = dot8_lanes(d2);
        float a_self = att_scalar(d1, b1v[6], w2v[6], b2v[6], 1.0f);
        float a_cust = att_scalar(d2, b1v[7], w2v[7], b2v[7], 1.0f);
        float sg = a_self + a_cust;
        float wi = a_self / sg, ws = a_cust / sg;
        #pragma unroll
        for (int j = 0; j < 8; j++)
            ac[j] = wi * sfi[j] + ws * ac[j];           // ac := i2 dims
    }

    // ---- final: sigmoid(u0.i0 + u1.i1 + u2.i2) ----
    float p = 0.f;
    #pragma unroll
    for (int j = 0; j < 8; j++) p += aa[j] * ac[j];
    p = dot8_lanes(p);                                  // u2.i2 (same in all lanes)
    float qd = u0[(size_t)ru * DIM + lane] * i0[(size_t)ri * DIM + lane]
             + u1[(size_t)ru * DIM + lane] * i1[(size_t)ri * DIM + lane];
    #pragma unroll
    for (int off = 32; off > 0; off >>= 1) qd += __shfl_xor(qd, off, 64);
    if (lane == 0) out[wid] = 1.0f / (1.0f + expf(-(p + qd)));
}

// ---------------- launch ----------------

extern "C" void kernel_launch(void* const* d_in, const int* in_sizes, int n_in,
                              void* d_out, int out_size, void* d_ws, size_t ws_size,
                              hipStream_t stream) {
    const float* user_emb = (const float*)d_in[0];
    const float* item_emb = (const float*)d_in[1];
    const float* snii1 = (const float*)d_in[2];
    const float* snii2 = (const float*)d_in[3];
    const float* ciii1 = (const float*)d_in[4];
    const float* ciii2 = (const float*)d_in[5];
    const float* icii1 = (const float*)d_in[6];
    const float* icii2 = (const float*)d_in[7];
    const float* low_w = (const float*)d_in[8];
    const float* low_b = (const float*)d_in[9];
    const float* att1_W = (const float*)d_in[10];
    const float* att1_b = (const float*)d_in[11];
    const float* att2_w = (const float*)d_in[12];
    const float* att2_b = (const float*)d_in[13];
    const int* sn_row = (const int*)d_in[14];
    const int* sn_col = (const int*)d_in[15];
    const int* ci_row = (const int*)d_in[16];
    const int* ci_col = (const int*)d_in[17];
    const int* ic_row = (const int*)d_in[18];
    const int* ic_col = (const int*)d_in[19];
    const int* user_idx = (const int*)d_in[20];
    const int* item_idx = (const int*)d_in[21];
    float* out = (float*)d_out;

    const int Es  = in_sizes[2];
    const int Eui = in_sizes[4];
    const int Eiu = in_sizes[6];
    const int U = in_sizes[0] / DIM;
    const int I = in_sizes[1] / DIM;
    const int B = in_sizes[20];
    const int R = 2 * U + I;                // virtual rows: [0,U)=sn, [U,2U)=ci, [2U,2U+I)=ic
    const int CB = (R + CBSZ - 1) / CBSZ;   // 245 coarse buckets <= CBMAX
    const int E = Es + Eui + Eiu;
    (void)E;

    // ---- workspace carve (4-byte units, 16B-aligned) ----
    char* wsb = (char*)d_ws;
    size_t off = 0;
    auto alloc = [&](size_t n_units) {
        off = (off + 3) & ~(size_t)3;
        void* p = wsb + off * 4; off += n_units; return p;
    };

    int* cnt    = (int*)alloc((size_t)NBLK_P * CB);
    int* blkoff = (int*)alloc((size_t)NBLK_P * CB);
    int* total  = (int*)alloc(CB);
    int* ptr    = (int*)alloc(R + 1);
    uint2* barr = (uint2*)alloc((size_t)E * 2);
    uint2* rec  = (uint2*)alloc((size_t)E * 2);
    uchar_t* ub8 = (uchar_t*)alloc((size_t)U * DIM / 4);
    uchar_t* ib8 = (uchar_t*)alloc((size_t)I * DIM / 4);
    float* u1  = (float*)alloc((size_t)U * DIM);
    float* i1  = (float*)alloc((size_t)I * DIM);
    (void)ws_size;

    size_t n8u = (size_t)U * DIM / 8, n8t = (size_t)(U + I) * DIM / 8;

    // ---- CSR build (4 dispatches): cvt+count | blkscan | place | finalize ----
    count_cvt_kernel<<<NBLK_P, NTHR, 0, stream>>>(user_emb, item_emb, ub8, ib8, n8u, n8t,
                                                  sn_row, ci_row, ic_row, cnt,
                                                  Es, Eui, Eiu, U, CB);
    blkscan_kernel<<<CB, NBLK_P, 0, stream>>>(cnt, blkoff, total, CB);
    place_kernel<<<NBLK_P, NTHR, 0, stream>>>(sn_row, sn_col, ci_row, ci_col, ic_row, ic_col,
                                              snii1, snii2, ciii1, ciii2, icii1, icii2,
                                              low_w, low_b, total, blkoff, barr,
                                              Es, Eui, Eiu, U, CB);
    finalize_kernel<<<CB, NTHR, 0, stream>>>(barr, total, ptr, rec, R, CB);

    // ---- layer 1: one row per 8-lane group, 32 rows per 256-thr block ----
    layer1_kernel<<<(U + I + 31) / 32, 256, 0, stream>>>(ub8, ib8, user_emb, item_emb,
        ptr, rec, att1_W, att1_b, att2_w, att2_b, u1, i1, U, I);

    // ---- fused layer2+final: one wave per sample ----
    l2f_kernel<<<(B + 3) / 4, 256, 0, stream>>>(user_emb, item_emb, u1, i1, ptr, rec,
        att1_W, att1_b, att2_w, att2_b, user_idx, item_idx, out, U, B);
}